// Round 4
// baseline (107.197 us; speedup 1.0000x reference)
//
#include <hip/hip_runtime.h>
#include <math.h>

#define NP 16384   // spatial positions = 32*32*16
#define HDIM 32
#define WDIM 32
#define ZDIM 16

typedef short bf16x8 __attribute__((ext_vector_type(8)));
typedef unsigned short u16x8 __attribute__((ext_vector_type(8)));
typedef float f32x4 __attribute__((ext_vector_type(4)));

__device__ __forceinline__ unsigned short f2bf(float f) {
    unsigned int u = __float_as_uint(f);
    return (unsigned short)((u + 0x7fffu + ((u >> 16) & 1u)) >> 16);
}
__device__ __forceinline__ float bf2f(unsigned short s) {
    return __uint_as_float(((unsigned int)s) << 16);
}

// ---------------------------------------------------------------------------
// x [128][NP] f32  ->  xT hi/lo bf16 planes [NP][128]
// ---------------------------------------------------------------------------
__global__ __launch_bounds__(256) void convert_x(
    const float* __restrict__ x, unsigned short* __restrict__ xhi,
    unsigned short* __restrict__ xlo)
{
    const int p = blockIdx.x * 256 + threadIdx.x;
    #pragma unroll
    for (int g = 0; g < 16; ++g) {
        u16x8 vh, vl;
        #pragma unroll
        for (int j = 0; j < 8; ++j) {
            const float v = x[(g * 8 + j) * NP + p];
            const unsigned short h = f2bf(v);
            vh[j] = h;
            vl[j] = f2bf(v - bf2f(h));
        }
        *(u16x8*)&xhi[p * 128 + g * 8] = vh;
        *(u16x8*)&xlo[p * 128 + g * 8] = vl;
    }
}

// ---------------------------------------------------------------------------
// Both weight matrices -> hi/lo bf16 planes. Blocks 0..23: Wqkv (6144 x8-elems),
// blocks 24..31: Wp (2048 x8-elems).
// ---------------------------------------------------------------------------
__global__ __launch_bounds__(256) void convert_w2(
    const float* __restrict__ Wqkv, unsigned short* __restrict__ wqh,
    unsigned short* __restrict__ wql,
    const float* __restrict__ Wp, unsigned short* __restrict__ wph,
    unsigned short* __restrict__ wpl)
{
    const float* W; unsigned short *oh, *ol; int e;
    if (blockIdx.x < 24) {
        W = Wqkv; oh = wqh; ol = wql;
        e = blockIdx.x * 256 + threadIdx.x;
    } else {
        W = Wp; oh = wph; ol = wpl;
        e = (blockIdx.x - 24) * 256 + threadIdx.x;
    }
    u16x8 vh, vl;
    #pragma unroll
    for (int j = 0; j < 8; ++j) {
        const float v = W[e * 8 + j];
        const unsigned short h = f2bf(v);
        vh[j] = h;
        vl[j] = f2bf(v - bf2f(h));
    }
    *(u16x8*)&oh[e * 8] = vh;
    *(u16x8*)&ol[e * 8] = vl;
}

// ---------------------------------------------------------------------------
// MFMA GEMM with bf16 hi/lo split: C = A . B^T + bias
// A planes: [M][128] bf16. B planes: [NP][128] bf16. K=128 in registers.
// TRANSC=0: C[o][p] f32 (ld NP).  TRANSC=1: C[p][o] f32 (ld 384), and rows
// <128 (the q block) are scaled by hd^-0.5 after bias (reference order).
// Block = 4 waves; wave: 16 rows x 64 cols. Grid: (NP/256, M/16).
// D-fragment: col=lane&15, row=(lane>>4)*4+reg  [m89-verified].
// ---------------------------------------------------------------------------
template<int TRANSC>
__global__ __launch_bounds__(256) void gemm_mfma_split(
    const unsigned short* __restrict__ Ahi, const unsigned short* __restrict__ Alo,
    const unsigned short* __restrict__ Bhi, const unsigned short* __restrict__ Blo,
    const float* __restrict__ bias, float* __restrict__ C)
{
    const int lane = threadIdx.x & 63;
    const int wv   = threadIdx.x >> 6;
    const int row0 = blockIdx.y * 16;
    const int colbase = blockIdx.x * 256 + wv * 64;
    const int rlane = lane & 15;
    const int kgrp  = lane >> 4;

    bf16x8 ah[4], al[4];
    {
        const int abase = (row0 + rlane) * 128 + kgrp * 8;
        #pragma unroll
        for (int kb = 0; kb < 4; ++kb) {
            ah[kb] = *(const bf16x8*)(Ahi + abase + kb * 32);
            al[kb] = *(const bf16x8*)(Alo + abase + kb * 32);
        }
    }
    float b4[4];
    #pragma unroll
    for (int r = 0; r < 4; ++r) b4[r] = bias[row0 + kgrp * 4 + r];
    const float rowscale = (TRANSC == 1 && row0 < 128) ? 0.17677669529663687f : 1.f;

    #pragma unroll
    for (int ct = 0; ct < 4; ++ct) {
        const int p = colbase + ct * 16 + rlane;
        f32x4 acc = {0.f, 0.f, 0.f, 0.f};
        #pragma unroll
        for (int kb = 0; kb < 4; ++kb) {
            const int boff = p * 128 + kb * 32 + kgrp * 8;
            const bf16x8 bh = *(const bf16x8*)(Bhi + boff);
            const bf16x8 bl = *(const bf16x8*)(Blo + boff);
            acc = __builtin_amdgcn_mfma_f32_16x16x32_bf16(ah[kb], bh, acc, 0, 0, 0);
            acc = __builtin_amdgcn_mfma_f32_16x16x32_bf16(ah[kb], bl, acc, 0, 0, 0);
            acc = __builtin_amdgcn_mfma_f32_16x16x32_bf16(al[kb], bh, acc, 0, 0, 0);
        }
        if (TRANSC == 0) {
            #pragma unroll
            for (int r = 0; r < 4; ++r)
                C[(row0 + kgrp * 4 + r) * NP + p] = acc[r] + b4[r];
        } else {
            float4 st;
            st.x = (acc[0] + b4[0]) * rowscale;
            st.y = (acc[1] + b4[1]) * rowscale;
            st.z = (acc[2] + b4[2]) * rowscale;
            st.w = (acc[3] + b4[3]) * rowscale;
            *(float4*)&C[(size_t)p * 384 + row0 + kgrp * 4] = st;
        }
    }
}

// ---------------------------------------------------------------------------
// 3D neighborhood attention, k=3x3x3, NATTEN clamped windows.
// qkvT f32 [NP][384]: q 0..127 (pre-scaled), k 128..255, v 256..383,
// channel-contiguous => all K/V neighbor reads are float4 pairs.
// 4 lanes per (head,pos): lane = z + 16*chunk, chunk owns 8 channels.
// Writes attnT hi/lo bf16 planes [NP][128]. Grid: (256, 4), 256 threads.
// ---------------------------------------------------------------------------
__global__ __launch_bounds__(256) void natten3d_v4(
    const float* __restrict__ qkvT, const float* __restrict__ rpb,
    unsigned short* __restrict__ athi, unsigned short* __restrict__ atlo)
{
    const int tid  = threadIdx.x;
    const int head = blockIdx.y;
    const int lane = tid & 63;
    const int wave = tid >> 6;
    const int z     = lane & 15;
    const int chunk = lane >> 4;
    const int col   = blockIdx.x * 4 + wave;
    const int h = col >> 5;
    const int w = col & 31;
    const int p = col * 16 + z;

    __shared__ float bias_s[125];
    if (tid < 125) bias_s[tid] = rpb[head * 125 + tid];
    __syncthreads();

    const int cb = head * 32 + chunk * 8;

    float q[8];
    {
        const float4 q0 = *(const float4*)&qkvT[(size_t)p * 384 + cb];
        const float4 q1 = *(const float4*)&qkvT[(size_t)p * 384 + cb + 4];
        q[0] = q0.x; q[1] = q0.y; q[2] = q0.z; q[3] = q0.w;
        q[4] = q1.x; q[5] = q1.y; q[6] = q1.z; q[7] = q1.w;
    }

    int hs = h - 1; hs = hs < 0 ? 0 : (hs > HDIM - 3 ? HDIM - 3 : hs);
    int ws_ = w - 1; ws_ = ws_ < 0 ? 0 : (ws_ > WDIM - 3 ? WDIM - 3 : ws_);
    int zs = z - 1; zs = zs < 0 ? 0 : (zs > ZDIM - 3 ? ZDIM - 3 : zs);
    const int rh0 = hs - h + 2;
    const int rw0 = ws_ - w + 2;
    const int rz0 = zs - z + 2;

    float s[27];
    float smax = -1e30f;
    #pragma unroll
    for (int dh = 0; dh < 3; ++dh) {
        #pragma unroll
        for (int dw = 0; dw < 3; ++dw) {
            #pragma unroll
            for (int dz = 0; dz < 3; ++dz) {
                const int m = (dh * 3 + dw) * 3 + dz;
                const int pn = (hs + dh) * 512 + (ws_ + dw) * 16 + (zs + dz);
                const float* kp = &qkvT[(size_t)pn * 384 + 128 + cb];
                const float4 k0 = *(const float4*)kp;
                const float4 k1 = *(const float4*)(kp + 4);
                float acc;
                acc = q[0] * k0.x;
                acc = fmaf(q[1], k0.y, acc);
                acc = fmaf(q[2], k0.z, acc);
                acc = fmaf(q[3], k0.w, acc);
                acc = fmaf(q[4], k1.x, acc);
                acc = fmaf(q[5], k1.y, acc);
                acc = fmaf(q[6], k1.z, acc);
                acc = fmaf(q[7], k1.w, acc);
                acc += __shfl_xor(acc, 16, 64);
                acc += __shfl_xor(acc, 32, 64);
                acc += bias_s[((rh0 + dh) * 5 + (rw0 + dw)) * 5 + (rz0 + dz)];
                s[m] = acc;
                smax = fmaxf(smax, acc);
            }
        }
    }

    float ssum = 0.f;
    #pragma unroll
    for (int m = 0; m < 27; ++m) {
        s[m] = __expf(s[m] - smax);
        ssum += s[m];
    }
    const float inv = 1.f / ssum;

    float o[8];
    #pragma unroll
    for (int d = 0; d < 8; ++d) o[d] = 0.f;

    #pragma unroll
    for (int dh = 0; dh < 3; ++dh) {
        #pragma unroll
        for (int dw = 0; dw < 3; ++dw) {
            #pragma unroll
            for (int dz = 0; dz < 3; ++dz) {
                const int m = (dh * 3 + dw) * 3 + dz;
                const int pn = (hs + dh) * 512 + (ws_ + dw) * 16 + (zs + dz);
                const float* vp = &qkvT[(size_t)pn * 384 + 256 + cb];
                const float4 v0 = *(const float4*)vp;
                const float4 v1 = *(const float4*)(vp + 4);
                const float pm = s[m];
                o[0] = fmaf(pm, v0.x, o[0]);
                o[1] = fmaf(pm, v0.y, o[1]);
                o[2] = fmaf(pm, v0.z, o[2]);
                o[3] = fmaf(pm, v0.w, o[3]);
                o[4] = fmaf(pm, v1.x, o[4]);
                o[5] = fmaf(pm, v1.y, o[5]);
                o[6] = fmaf(pm, v1.z, o[6]);
                o[7] = fmaf(pm, v1.w, o[7]);
            }
        }
    }

    u16x8 vh, vl;
    #pragma unroll
    for (int d = 0; d < 8; ++d) {
        const float val = o[d] * inv;
        const unsigned short hh = f2bf(val);
        vh[d] = hh;
        vl[d] = f2bf(val - bf2f(hh));
    }
    *(u16x8*)&athi[p * 128 + cb] = vh;
    *(u16x8*)&atlo[p * 128 + cb] = vl;
}

// ---------------------------------------------------------------------------
extern "C" void kernel_launch(void* const* d_in, const int* in_sizes, int n_in,
                              void* d_out, int out_size, void* d_ws, size_t ws_size,
                              hipStream_t stream)
{
    const float* x    = (const float*)d_in[0];  // (1,128,32,32,16)
    const float* Wqkv = (const float*)d_in[1];  // (384,128)
    const float* bqkv = (const float*)d_in[2];  // (384,)
    const float* rpb  = (const float*)d_in[3];  // (4,5,5,5)
    const float* Wp   = (const float*)d_in[4];  // (128,128)
    const float* bp   = (const float*)d_in[5];  // (128,)
    float* out = (float*)d_out;                 // (1,128,32,32,16)

    float* qkvT = (float*)d_ws;                       // [NP][384] f32 = 24 MB
    unsigned short* base = (unsigned short*)(qkvT + (size_t)384 * NP);
    unsigned short* xhi  = base;                      // [NP][128] bf16, 4 MB each
    unsigned short* xlo  = base + (size_t)NP * 128;
    unsigned short* athi = base + (size_t)2 * NP * 128;
    unsigned short* atlo = base + (size_t)3 * NP * 128;
    unsigned short* wqh  = base + (size_t)4 * NP * 128;
    unsigned short* wql  = wqh + 384 * 128;
    unsigned short* wph  = wql + 384 * 128;
    unsigned short* wpl  = wph + 128 * 128;

    convert_x<<<dim3(NP / 256), dim3(256), 0, stream>>>(x, xhi, xlo);
    convert_w2<<<dim3(32), dim3(256), 0, stream>>>(Wqkv, wqh, wql, Wp, wph, wpl);

    // 1) QKV projection -> transposed f32 qkvT[p][384], q rows pre-scaled
    gemm_mfma_split<1><<<dim3(NP / 256, 384 / 16), dim3(256), 0, stream>>>(
        wqh, wql, xhi, xlo, bqkv, qkvT);

    // 2) neighborhood attention -> bf16 transposed hi/lo planes
    natten3d_v4<<<dim3(256, 4), dim3(256), 0, stream>>>(qkvT, rpb, athi, atlo);

    // 3) output projection -> f32 out [128][NP]
    gemm_mfma_split<0><<<dim3(NP / 256, 128 / 16), dim3(256), 0, stream>>>(
        wph, wpl, athi, atlo, bp, out);
}

// Round 5
// 78.715 us; speedup vs baseline: 1.3618x; 1.3618x over previous
//
#include <hip/hip_runtime.h>
#include <math.h>

#define NP 16384   // spatial positions = 32*32*16
#define HDIM 32
#define WDIM 32
#define ZDIM 16

typedef short bf16x8 __attribute__((ext_vector_type(8)));
typedef unsigned short u16x8 __attribute__((ext_vector_type(8)));
typedef unsigned short u16x4 __attribute__((ext_vector_type(4)));
typedef float f32x4 __attribute__((ext_vector_type(4)));

__device__ __forceinline__ unsigned short f2bf(float f) {
    unsigned int u = __float_as_uint(f);
    return (unsigned short)((u + 0x7fffu + ((u >> 16) & 1u)) >> 16);
}
__device__ __forceinline__ float bf2f(unsigned short s) {
    return __uint_as_float(((unsigned int)s) << 16);
}

// ---------------------------------------------------------------------------
// x [128][NP] f32 -> xT hi/lo bf16 planes [NP][128].  Grid (NP/256, 16).
// Block (bx, by): positions bx*256..+255, channels by*8..+7.
// ---------------------------------------------------------------------------
__global__ __launch_bounds__(256) void convert_x(
    const float* __restrict__ x, unsigned short* __restrict__ xhi,
    unsigned short* __restrict__ xlo)
{
    const int p  = blockIdx.x * 256 + threadIdx.x;
    const int c0 = blockIdx.y * 8;
    u16x8 vh, vl;
    #pragma unroll
    for (int j = 0; j < 8; ++j) {
        const float v = x[(c0 + j) * NP + p];
        const unsigned short h = f2bf(v);
        vh[j] = h;
        vl[j] = f2bf(v - bf2f(h));
    }
    *(u16x8*)&xhi[p * 128 + c0] = vh;
    *(u16x8*)&xlo[p * 128 + c0] = vl;
}

// ---------------------------------------------------------------------------
// Weight conversion: blocks 0..23 Wqkv, 24..31 Wp.
// ---------------------------------------------------------------------------
__global__ __launch_bounds__(256) void convert_w2(
    const float* __restrict__ Wqkv, unsigned short* __restrict__ wqh,
    unsigned short* __restrict__ wql,
    const float* __restrict__ Wp, unsigned short* __restrict__ wph,
    unsigned short* __restrict__ wpl)
{
    const float* W; unsigned short *oh, *ol; int e;
    if (blockIdx.x < 24) {
        W = Wqkv; oh = wqh; ol = wql;
        e = blockIdx.x * 256 + threadIdx.x;
    } else {
        W = Wp; oh = wph; ol = wpl;
        e = (blockIdx.x - 24) * 256 + threadIdx.x;
    }
    u16x8 vh, vl;
    #pragma unroll
    for (int j = 0; j < 8; ++j) {
        const float v = W[e * 8 + j];
        const unsigned short h = f2bf(v);
        vh[j] = h;
        vl[j] = f2bf(v - bf2f(h));
    }
    *(u16x8*)&oh[e * 8] = vh;
    *(u16x8*)&ol[e * 8] = vl;
}

// ---------------------------------------------------------------------------
// QKV GEMM (hi/lo split MFMA): rows 0..127 -> Q[p][ch] (scaled), 128..255 ->
// K[p][ch], 256..383 -> V^T[ch][p].  All outputs bf16 hi/lo.
// A: weights [384][128] bf16 planes; B: xT [NP][128] bf16 planes.
// Block 4 waves, wave: 16 rows x 64 cols. Grid (NP/256, 24).
// ---------------------------------------------------------------------------
__global__ __launch_bounds__(256) void qkv_gemm(
    const unsigned short* __restrict__ Ahi, const unsigned short* __restrict__ Alo,
    const unsigned short* __restrict__ Bhi, const unsigned short* __restrict__ Blo,
    const float* __restrict__ bias,
    unsigned short* __restrict__ Qhi, unsigned short* __restrict__ Qlo,
    unsigned short* __restrict__ Khi, unsigned short* __restrict__ Klo,
    unsigned short* __restrict__ VThi, unsigned short* __restrict__ VTlo)
{
    const int lane = threadIdx.x & 63;
    const int wv   = threadIdx.x >> 6;
    const int row0 = blockIdx.y * 16;
    const int colbase = blockIdx.x * 256 + wv * 64;
    const int rlane = lane & 15;
    const int kgrp  = lane >> 4;

    bf16x8 ah[4], al[4];
    {
        const int abase = (row0 + rlane) * 128 + kgrp * 8;
        #pragma unroll
        for (int kb = 0; kb < 4; ++kb) {
            ah[kb] = *(const bf16x8*)(Ahi + abase + kb * 32);
            al[kb] = *(const bf16x8*)(Alo + abase + kb * 32);
        }
    }
    float b4[4];
    #pragma unroll
    for (int r = 0; r < 4; ++r) b4[r] = bias[row0 + kgrp * 4 + r];
    const float rowscale = (row0 < 128) ? 0.17677669529663687f : 1.f;

    #pragma unroll
    for (int ct = 0; ct < 4; ++ct) {
        const int p = colbase + ct * 16 + rlane;
        f32x4 acc = {0.f, 0.f, 0.f, 0.f};
        #pragma unroll
        for (int kb = 0; kb < 4; ++kb) {
            const int boff = p * 128 + kb * 32 + kgrp * 8;
            const bf16x8 bh = *(const bf16x8*)(Bhi + boff);
            const bf16x8 bl = *(const bf16x8*)(Blo + boff);
            acc = __builtin_amdgcn_mfma_f32_16x16x32_bf16(ah[kb], bh, acc, 0, 0, 0);
            acc = __builtin_amdgcn_mfma_f32_16x16x32_bf16(ah[kb], bl, acc, 0, 0, 0);
            acc = __builtin_amdgcn_mfma_f32_16x16x32_bf16(al[kb], bh, acc, 0, 0, 0);
        }
        float val[4];
        unsigned short hh[4], ll[4];
        #pragma unroll
        for (int r = 0; r < 4; ++r) {
            val[r] = (acc[r] + b4[r]) * rowscale;
            hh[r] = f2bf(val[r]);
            ll[r] = f2bf(val[r] - bf2f(hh[r]));
        }
        if (row0 < 128) {
            u16x4 ph = {hh[0], hh[1], hh[2], hh[3]};
            u16x4 pl = {ll[0], ll[1], ll[2], ll[3]};
            *(u16x4*)&Qhi[p * 128 + row0 + kgrp * 4] = ph;
            *(u16x4*)&Qlo[p * 128 + row0 + kgrp * 4] = pl;
        } else if (row0 < 256) {
            u16x4 ph = {hh[0], hh[1], hh[2], hh[3]};
            u16x4 pl = {ll[0], ll[1], ll[2], ll[3]};
            *(u16x4*)&Khi[p * 128 + (row0 - 128) + kgrp * 4] = ph;
            *(u16x4*)&Klo[p * 128 + (row0 - 128) + kgrp * 4] = pl;
        } else {
            #pragma unroll
            for (int r = 0; r < 4; ++r) {
                const int ch = row0 - 256 + kgrp * 4 + r;
                VThi[ch * NP + p] = hh[r];
                VTlo[ch * NP + p] = ll[r];
            }
        }
    }
}

// ---------------------------------------------------------------------------
// MFMA neighborhood attention.  One wave = one (head, h, w) unit: 16 queries
// (z) x 144 keys (9 hw-neighbors x 16 z), masked to the 27 valid per query.
// S^T = mfma(K_frag, Q_frag) per key-group (hi/lo split, 3 mfma).
// Softmax per q-column: 2 shfl_xor.  P -> per-wave LDS slice (swizzled),
// PV = mfma(P_frag, V^T_frag) with V^T[ch][NP] bf16 hi/lo.
// Block = 8 waves (8 w's, same h, same head).  Grid (4, 32, 4).
// ---------------------------------------------------------------------------
#define PADK 160
#define PROW (PADK * 2)        // 320 B per q-row
#define PWAVE (16 * PROW)      // 5120 B per wave

__global__ __launch_bounds__(512) void natten_mfma(
    const unsigned short* __restrict__ Qhi, const unsigned short* __restrict__ Qlo,
    const unsigned short* __restrict__ Khi, const unsigned short* __restrict__ Klo,
    const unsigned short* __restrict__ VThi, const unsigned short* __restrict__ VTlo,
    const float* __restrict__ rpb,
    unsigned short* __restrict__ athi, unsigned short* __restrict__ atlo)
{
    __shared__ __align__(16) unsigned char Pl[8 * PWAVE];   // 40 KB
    __shared__ float bias_s[128];

    const int tid  = threadIdx.x;
    const int head = blockIdx.z;
    const int h    = blockIdx.y;
    const int wv   = tid >> 6;
    const int w    = blockIdx.x * 8 + wv;
    const int lane = tid & 63;
    const int l15  = lane & 15;
    const int kg   = lane >> 4;

    if (tid < 125) bias_s[tid] = rpb[head * 125 + tid];
    __syncthreads();

    const int hs = min(max(h - 1, 0), HDIM - 3);
    const int ws = min(max(w - 1, 0), WDIM - 3);
    const int rh0 = hs - h + 2, rw0 = ws - w + 2;
    const int pcol = (h * 32 + w) * 16;
    const int cb = head * 32;

    // Q B-fragment (col = q = l15, k = ch)
    const bf16x8 bq_h = *(const bf16x8*)&Qhi[(pcol + l15) * 128 + cb + kg * 8];
    const bf16x8 bq_l = *(const bf16x8*)&Qlo[(pcol + l15) * 128 + cb + kg * 8];

    const int z  = l15;                       // this lane's q-column
    const int zs = min(max(z - 1, 0), ZDIM - 3);

    float sv[9][4];
    float m = -1e30f;
    #pragma unroll
    for (int g = 0; g < 9; ++g) {
        const int dh = g / 3, dw = g % 3;
        const int pn = ((hs + dh) * 32 + (ws + dw)) * 16;
        // K A-fragment (row = key z' = l15, k = ch)
        const bf16x8 ak_h = *(const bf16x8*)&Khi[(pn + l15) * 128 + cb + kg * 8];
        const bf16x8 ak_l = *(const bf16x8*)&Klo[(pn + l15) * 128 + cb + kg * 8];
        f32x4 st = {0.f, 0.f, 0.f, 0.f};
        st = __builtin_amdgcn_mfma_f32_16x16x32_bf16(ak_h, bq_h, st, 0, 0, 0);
        st = __builtin_amdgcn_mfma_f32_16x16x32_bf16(ak_h, bq_l, st, 0, 0, 0);
        st = __builtin_amdgcn_mfma_f32_16x16x32_bf16(ak_l, bq_h, st, 0, 0, 0);
        const int bbase = ((rh0 + dh) * 5 + (rw0 + dw)) * 5;
        #pragma unroll
        for (int r = 0; r < 4; ++r) {
            const int zp = kg * 4 + r;            // key z' (D row)
            const int dz = zp - z + 2;
            const bool valid = (zp >= zs) && (zp <= zs + 2);
            const int idx = min(max(dz, 0), 4);
            const float b = valid ? bias_s[bbase + idx] : -1e30f;
            sv[g][r] = st[r] + b;
            m = fmaxf(m, sv[g][r]);
        }
    }
    m = fmaxf(m, __shfl_xor(m, 16, 64));
    m = fmaxf(m, __shfl_xor(m, 32, 64));

    float sum = 0.f;
    #pragma unroll
    for (int g = 0; g < 9; ++g)
        #pragma unroll
        for (int r = 0; r < 4; ++r) {
            sv[g][r] = __expf(sv[g][r] - m);
            sum += sv[g][r];
        }
    sum += __shfl_xor(sum, 16, 64);
    sum += __shfl_xor(sum, 32, 64);
    const float inv = 1.f / sum;

    // write P (bf16, unnormalized) to this wave's LDS slice, XOR-swizzled
    unsigned char* Pw = &Pl[wv * PWAVE];
    #pragma unroll
    for (int g = 0; g < 9; ++g) {
        u16x4 pk;
        #pragma unroll
        for (int r = 0; r < 4; ++r) pk[r] = f2bf(sv[g][r]);
        const int off = (z * PROW + (16 * g + kg * 4) * 2) ^ ((z & 7) << 4);
        *(u16x4*)(Pw + off) = pk;
    }
    {   // zero-pad keys 144..159
        u16x4 zq = {0, 0, 0, 0};
        const int off = (z * PROW + (144 + kg * 4) * 2) ^ ((z & 7) << 4);
        *(u16x4*)(Pw + off) = zq;
    }

    // inv for output rows q' = kg*4+r (PV D-layout)
    float invr[4];
    #pragma unroll
    for (int r = 0; r < 4; ++r)
        invr[r] = __shfl(inv, (lane & 48) | (kg * 4 + r), 64);

    // PV: out(q, ch) over 2 ch-tiles, K-dim = 160 keys (5 chunks of 32)
    #pragma unroll
    for (int ct = 0; ct < 2; ++ct) {
        f32x4 acc = {0.f, 0.f, 0.f, 0.f};
        #pragma unroll
        for (int kb = 0; kb < 5; ++kb) {
            const int off = (z * PROW + (kb * 32 + kg * 8) * 2) ^ ((z & 7) << 4);
            const bf16x8 ap = *(const bf16x8*)(Pw + off);
            // key group for this lane-quarter: ga = 2kb (kg<2), gb = 2kb+1 (kg>=2)
            const int ga = 2 * kb;
            const int gb = (2 * kb + 1 > 8) ? 8 : 2 * kb + 1;
            const int pna = ((hs + ga / 3) * 32 + (ws + ga % 3)) * 16;
            const int pnbv = ((hs + gb / 3) * 32 + (ws + gb % 3)) * 16;
            const int pn = (kg & 2) ? pnbv : pna;
            const int zoff = (kg & 1) * 8;
            const int vbase = (cb + ct * 16 + l15) * NP + pn + zoff;
            const bf16x8 bv_h = *(const bf16x8*)&VThi[vbase];
            const bf16x8 bv_l = *(const bf16x8*)&VTlo[vbase];
            acc = __builtin_amdgcn_mfma_f32_16x16x32_bf16(ap, bv_h, acc, 0, 0, 0);
            acc = __builtin_amdgcn_mfma_f32_16x16x32_bf16(ap, bv_l, acc, 0, 0, 0);
        }
        #pragma unroll
        for (int r = 0; r < 4; ++r) {
            const int qp = kg * 4 + r;
            const float val = acc[r] * invr[r];
            const unsigned short hh = f2bf(val);
            const unsigned short ll = f2bf(val - bf2f(hh));
            athi[(pcol + qp) * 128 + cb + ct * 16 + l15] = hh;
            atlo[(pcol + qp) * 128 + cb + ct * 16 + l15] = ll;
        }
    }
}

// ---------------------------------------------------------------------------
// Output projection (hi/lo split MFMA): out[o][p] f32 = Wp[o,:] . attn[p,:]^T
// ---------------------------------------------------------------------------
__global__ __launch_bounds__(256) void gemm_proj(
    const unsigned short* __restrict__ Ahi, const unsigned short* __restrict__ Alo,
    const unsigned short* __restrict__ Bhi, const unsigned short* __restrict__ Blo,
    const float* __restrict__ bias, float* __restrict__ C)
{
    const int lane = threadIdx.x & 63;
    const int wv   = threadIdx.x >> 6;
    const int row0 = blockIdx.y * 16;
    const int colbase = blockIdx.x * 256 + wv * 64;
    const int rlane = lane & 15;
    const int kgrp  = lane >> 4;

    bf16x8 ah[4], al[4];
    {
        const int abase = (row0 + rlane) * 128 + kgrp * 8;
        #pragma unroll
        for (int kb = 0; kb < 4; ++kb) {
            ah[kb] = *(const bf16x8*)(Ahi + abase + kb * 32);
            al[kb] = *(const bf16x8*)(Alo + abase + kb * 32);
        }
    }
    float b4[4];
    #pragma unroll
    for (int r = 0; r < 4; ++r) b4[r] = bias[row0 + kgrp * 4 + r];

    #pragma unroll
    for (int ct = 0; ct < 4; ++ct) {
        const int p = colbase + ct * 16 + rlane;
        f32x4 acc = {0.f, 0.f, 0.f, 0.f};
        #pragma unroll
        for (int kb = 0; kb < 4; ++kb) {
            const int boff = p * 128 + kb * 32 + kgrp * 8;
            const bf16x8 bh = *(const bf16x8*)(Bhi + boff);
            const bf16x8 bl = *(const bf16x8*)(Blo + boff);
            acc = __builtin_amdgcn_mfma_f32_16x16x32_bf16(ah[kb], bh, acc, 0, 0, 0);
            acc = __builtin_amdgcn_mfma_f32_16x16x32_bf16(ah[kb], bl, acc, 0, 0, 0);
            acc = __builtin_amdgcn_mfma_f32_16x16x32_bf16(al[kb], bh, acc, 0, 0, 0);
        }
        #pragma unroll
        for (int r = 0; r < 4; ++r)
            C[(row0 + kgrp * 4 + r) * NP + p] = acc[r] + b4[r];
    }
}

// ---------------------------------------------------------------------------
extern "C" void kernel_launch(void* const* d_in, const int* in_sizes, int n_in,
                              void* d_out, int out_size, void* d_ws, size_t ws_size,
                              hipStream_t stream)
{
    const float* x    = (const float*)d_in[0];
    const float* Wqkv = (const float*)d_in[1];
    const float* bqkv = (const float*)d_in[2];
    const float* rpb  = (const float*)d_in[3];
    const float* Wp   = (const float*)d_in[4];
    const float* bp   = (const float*)d_in[5];
    float* out = (float*)d_out;

    unsigned short* base = (unsigned short*)d_ws;
    const size_t PL = (size_t)NP * 128;
    unsigned short* xhi  = base;
    unsigned short* xlo  = base + PL;
    unsigned short* Qhi  = base + 2 * PL;
    unsigned short* Qlo  = base + 3 * PL;
    unsigned short* Khi  = base + 4 * PL;
    unsigned short* Klo  = base + 5 * PL;
    unsigned short* VThi = base + 6 * PL;   // [128][NP]
    unsigned short* VTlo = base + 7 * PL;
    unsigned short* athi = base + 8 * PL;
    unsigned short* atlo = base + 9 * PL;
    unsigned short* wqh  = base + 10 * PL;
    unsigned short* wql  = wqh + 384 * 128;
    unsigned short* wph  = wql + 384 * 128;
    unsigned short* wpl  = wph + 128 * 128;

    convert_x<<<dim3(NP / 256, 16), dim3(256), 0, stream>>>(x, xhi, xlo);
    convert_w2<<<dim3(32), dim3(256), 0, stream>>>(Wqkv, wqh, wql, Wp, wph, wpl);

    qkv_gemm<<<dim3(NP / 256, 24), dim3(256), 0, stream>>>(
        wqh, wql, xhi, xlo, bqkv, Qhi, Qlo, Khi, Klo, VThi, VTlo);

    natten_mfma<<<dim3(4, 32, 4), dim3(512), 0, stream>>>(
        Qhi, Qlo, Khi, Klo, VThi, VTlo, rpb, athi, atlo);

    gemm_proj<<<dim3(NP / 256, 8), dim3(256), 0, stream>>>(
        wph, wpl, athi, atlo, bp, out);
}

// Round 6
// 53.239 us; speedup vs baseline: 2.0135x; 1.4785x over previous
//
#include <hip/hip_runtime.h>
#include <math.h>

#define NP 16384   // spatial positions = 32*32*16
#define HDIM 32
#define WDIM 32
#define ZDIM 16

typedef short bf16x8 __attribute__((ext_vector_type(8)));
typedef unsigned short u16x8 __attribute__((ext_vector_type(8)));
typedef unsigned short u16x4 __attribute__((ext_vector_type(4)));
typedef float f32x4 __attribute__((ext_vector_type(4)));

__device__ __forceinline__ unsigned short f2bf(float f) {
    unsigned int u = __float_as_uint(f);
    return (unsigned short)((u + 0x7fffu + ((u >> 16) & 1u)) >> 16);
}
__device__ __forceinline__ float bf2f(unsigned short s) {
    return __uint_as_float(((unsigned int)s) << 16);
}

// ---------------------------------------------------------------------------
// Combined conversion kernel.
// Blocks 0..1023: x [128][NP] f32 -> xT hi/lo bf16 [NP][128] (block b: 256
// positions, 8 channels).  Blocks 1024..1047: Wqkv hi/lo. 1048..1055: Wp hi/lo.
// ---------------------------------------------------------------------------
__global__ __launch_bounds__(256) void convert_all(
    const float* __restrict__ x, unsigned short* __restrict__ xhi,
    unsigned short* __restrict__ xlo,
    const float* __restrict__ Wqkv, unsigned short* __restrict__ wqh,
    unsigned short* __restrict__ wql,
    const float* __restrict__ Wp, unsigned short* __restrict__ wph,
    unsigned short* __restrict__ wpl)
{
    const int b = blockIdx.x;
    if (b < 1024) {
        const int p  = (b >> 4) * 256 + threadIdx.x;
        const int c0 = (b & 15) * 8;
        u16x8 vh, vl;
        #pragma unroll
        for (int j = 0; j < 8; ++j) {
            const float v = x[(c0 + j) * NP + p];
            const unsigned short h = f2bf(v);
            vh[j] = h;
            vl[j] = f2bf(v - bf2f(h));
        }
        *(u16x8*)&xhi[p * 128 + c0] = vh;
        *(u16x8*)&xlo[p * 128 + c0] = vl;
    } else {
        const float* W; unsigned short *oh, *ol; int e;
        if (b < 1048) {
            W = Wqkv; oh = wqh; ol = wql;
            e = (b - 1024) * 256 + threadIdx.x;
        } else {
            W = Wp; oh = wph; ol = wpl;
            e = (b - 1048) * 256 + threadIdx.x;
        }
        u16x8 vh, vl;
        #pragma unroll
        for (int j = 0; j < 8; ++j) {
            const float v = W[e * 8 + j];
            const unsigned short h = f2bf(v);
            vh[j] = h;
            vl[j] = f2bf(v - bf2f(h));
        }
        *(u16x8*)&oh[e * 8] = vh;
        *(u16x8*)&ol[e * 8] = vl;
    }
}

// ---------------------------------------------------------------------------
// QKV GEMM (hi/lo split inputs, bf16 single-plane outputs).
// rows 0..127 -> Q[p][ch] (scaled), 128..255 -> K[p][ch], 256..383 -> VT[ch][p].
// Wave computes 32 rows x 64 cols (2 row-groups share B fragments).
// Grid (NP/256, 384/32=12), 256 threads.
// ---------------------------------------------------------------------------
__global__ __launch_bounds__(256) void qkv_gemm(
    const unsigned short* __restrict__ Ahi, const unsigned short* __restrict__ Alo,
    const unsigned short* __restrict__ Bhi, const unsigned short* __restrict__ Blo,
    const float* __restrict__ bias,
    unsigned short* __restrict__ Qb, unsigned short* __restrict__ Kb,
    unsigned short* __restrict__ VTb)
{
    const int lane = threadIdx.x & 63;
    const int wv   = threadIdx.x >> 6;
    const int row0 = blockIdx.y * 32;
    const int colbase = blockIdx.x * 256 + wv * 64;
    const int rlane = lane & 15;
    const int kgrp  = lane >> 4;

    bf16x8 ah0[4], al0[4], ah1[4], al1[4];
    {
        const int ab0 = (row0 + rlane) * 128 + kgrp * 8;
        const int ab1 = (row0 + 16 + rlane) * 128 + kgrp * 8;
        #pragma unroll
        for (int kb = 0; kb < 4; ++kb) {
            ah0[kb] = *(const bf16x8*)(Ahi + ab0 + kb * 32);
            al0[kb] = *(const bf16x8*)(Alo + ab0 + kb * 32);
            ah1[kb] = *(const bf16x8*)(Ahi + ab1 + kb * 32);
            al1[kb] = *(const bf16x8*)(Alo + ab1 + kb * 32);
        }
    }
    float b40[4], b41[4];
    #pragma unroll
    for (int r = 0; r < 4; ++r) {
        b40[r] = bias[row0 + kgrp * 4 + r];
        b41[r] = bias[row0 + 16 + kgrp * 4 + r];
    }
    const float rowscale = (row0 < 128) ? 0.17677669529663687f : 1.f;

    #pragma unroll
    for (int ct = 0; ct < 4; ++ct) {
        const int p = colbase + ct * 16 + rlane;
        f32x4 acc0 = {0.f, 0.f, 0.f, 0.f};
        f32x4 acc1 = {0.f, 0.f, 0.f, 0.f};
        #pragma unroll
        for (int kb = 0; kb < 4; ++kb) {
            const int boff = p * 128 + kb * 32 + kgrp * 8;
            const bf16x8 bh = *(const bf16x8*)(Bhi + boff);
            const bf16x8 bl = *(const bf16x8*)(Blo + boff);
            acc0 = __builtin_amdgcn_mfma_f32_16x16x32_bf16(ah0[kb], bh, acc0, 0, 0, 0);
            acc0 = __builtin_amdgcn_mfma_f32_16x16x32_bf16(ah0[kb], bl, acc0, 0, 0, 0);
            acc0 = __builtin_amdgcn_mfma_f32_16x16x32_bf16(al0[kb], bh, acc0, 0, 0, 0);
            acc1 = __builtin_amdgcn_mfma_f32_16x16x32_bf16(ah1[kb], bh, acc1, 0, 0, 0);
            acc1 = __builtin_amdgcn_mfma_f32_16x16x32_bf16(ah1[kb], bl, acc1, 0, 0, 0);
            acc1 = __builtin_amdgcn_mfma_f32_16x16x32_bf16(al1[kb], bh, acc1, 0, 0, 0);
        }
        #pragma unroll
        for (int rg = 0; rg < 2; ++rg) {
            const int r0 = row0 + rg * 16;
            unsigned short hh[4];
            #pragma unroll
            for (int r = 0; r < 4; ++r) {
                const float a = rg ? acc1[r] : acc0[r];
                const float bb = rg ? b41[r] : b40[r];
                hh[r] = f2bf((a + bb) * rowscale);
            }
            if (r0 < 128) {
                u16x4 ph = {hh[0], hh[1], hh[2], hh[3]};
                *(u16x4*)&Qb[p * 128 + r0 + kgrp * 4] = ph;
            } else if (r0 < 256) {
                u16x4 ph = {hh[0], hh[1], hh[2], hh[3]};
                *(u16x4*)&Kb[p * 128 + (r0 - 128) + kgrp * 4] = ph;
            } else {
                #pragma unroll
                for (int r = 0; r < 4; ++r)
                    VTb[(r0 - 256 + kgrp * 4 + r) * NP + p] = hh[r];
            }
        }
    }
}

// ---------------------------------------------------------------------------
// MFMA neighborhood attention (single-plane bf16 Q/K/V).
// One wave = one (head, h, w): 16 queries (z) x 144 keys (9 hw-nbrs x 16 z),
// masked to 27 valid per query.  S^T = mfma(K,Q) per key-group (9 MFMA).
// Softmax per q-column (2 shfl_xor).  P bf16 -> per-wave swizzled LDS.
// PV = mfma(P, V^T) (10 MFMA).  Block = 8 waves.  Grid (4, 32, 4).
// ---------------------------------------------------------------------------
#define PADK 160
#define PROW (PADK * 2)        // 320 B per q-row
#define PWAVE (16 * PROW)      // 5120 B per wave

__global__ __launch_bounds__(512) void natten_mfma(
    const unsigned short* __restrict__ Qb, const unsigned short* __restrict__ Kb,
    const unsigned short* __restrict__ VTb,
    const float* __restrict__ rpb,
    unsigned short* __restrict__ atb)
{
    __shared__ __align__(16) unsigned char Pl[8 * PWAVE];   // 40 KB
    __shared__ float bias_s[128];

    const int tid  = threadIdx.x;
    const int head = blockIdx.z;
    const int h    = blockIdx.y;
    const int wv   = tid >> 6;
    const int w    = blockIdx.x * 8 + wv;
    const int lane = tid & 63;
    const int l15  = lane & 15;
    const int kg   = lane >> 4;

    if (tid < 125) bias_s[tid] = rpb[head * 125 + tid];
    __syncthreads();

    const int hs = min(max(h - 1, 0), HDIM - 3);
    const int ws = min(max(w - 1, 0), WDIM - 3);
    const int rh0 = hs - h + 2, rw0 = ws - w + 2;
    const int pcol = (h * 32 + w) * 16;
    const int cb = head * 32;

    // Q B-fragment (col = q = l15, k = ch)
    const bf16x8 bq = *(const bf16x8*)&Qb[(pcol + l15) * 128 + cb + kg * 8];

    const int z  = l15;
    const int zs = min(max(z - 1, 0), ZDIM - 3);

    float sv[9][4];
    float m = -1e30f;
    #pragma unroll
    for (int g = 0; g < 9; ++g) {
        const int dh = g / 3, dw = g % 3;
        const int pn = ((hs + dh) * 32 + (ws + dw)) * 16;
        const bf16x8 ak = *(const bf16x8*)&Kb[(pn + l15) * 128 + cb + kg * 8];
        f32x4 st = {0.f, 0.f, 0.f, 0.f};
        st = __builtin_amdgcn_mfma_f32_16x16x32_bf16(ak, bq, st, 0, 0, 0);
        const int bbase = ((rh0 + dh) * 5 + (rw0 + dw)) * 5;
        #pragma unroll
        for (int r = 0; r < 4; ++r) {
            const int zp = kg * 4 + r;            // key z' (D row)
            const int dz = zp - z + 2;
            const bool valid = (zp >= zs) && (zp <= zs + 2);
            const int idx = min(max(dz, 0), 4);
            const float b = valid ? bias_s[bbase + idx] : -1e30f;
            sv[g][r] = st[r] + b;
            m = fmaxf(m, sv[g][r]);
        }
    }
    m = fmaxf(m, __shfl_xor(m, 16, 64));
    m = fmaxf(m, __shfl_xor(m, 32, 64));

    float sum = 0.f;
    #pragma unroll
    for (int g = 0; g < 9; ++g)
        #pragma unroll
        for (int r = 0; r < 4; ++r) {
            sv[g][r] = __expf(sv[g][r] - m);
            sum += sv[g][r];
        }
    sum += __shfl_xor(sum, 16, 64);
    sum += __shfl_xor(sum, 32, 64);
    const float inv = 1.f / sum;

    // P (bf16, unnormalized) -> this wave's LDS slice, XOR-swizzled
    unsigned char* Pw = &Pl[wv * PWAVE];
    #pragma unroll
    for (int g = 0; g < 9; ++g) {
        u16x4 pk;
        #pragma unroll
        for (int r = 0; r < 4; ++r) pk[r] = f2bf(sv[g][r]);
        const int off = (z * PROW + (16 * g + kg * 4) * 2) ^ ((z & 7) << 4);
        *(u16x4*)(Pw + off) = pk;
    }
    {   // zero-pad keys 144..159
        u16x4 zq = {0, 0, 0, 0};
        const int off = (z * PROW + (144 + kg * 4) * 2) ^ ((z & 7) << 4);
        *(u16x4*)(Pw + off) = zq;
    }

    float invr[4];
    #pragma unroll
    for (int r = 0; r < 4; ++r)
        invr[r] = __shfl(inv, (lane & 48) | (kg * 4 + r), 64);

    // PV: out(q, ch) over 2 ch-tiles, K-dim = 160 keys (5 chunks of 32)
    #pragma unroll
    for (int ct = 0; ct < 2; ++ct) {
        f32x4 acc = {0.f, 0.f, 0.f, 0.f};
        #pragma unroll
        for (int kb = 0; kb < 5; ++kb) {
            const int off = (z * PROW + (kb * 32 + kg * 8) * 2) ^ ((z & 7) << 4);
            const bf16x8 ap = *(const bf16x8*)(Pw + off);
            const int ga = 2 * kb;
            const int gb = (2 * kb + 1 > 8) ? 8 : 2 * kb + 1;
            const int pna = ((hs + ga / 3) * 32 + (ws + ga % 3)) * 16;
            const int pnbv = ((hs + gb / 3) * 32 + (ws + gb % 3)) * 16;
            const int pn = (kg & 2) ? pnbv : pna;
            const int zoff = (kg & 1) * 8;
            const bf16x8 bv = *(const bf16x8*)&VTb[(cb + ct * 16 + l15) * NP + pn + zoff];
            acc = __builtin_amdgcn_mfma_f32_16x16x32_bf16(ap, bv, acc, 0, 0, 0);
        }
        #pragma unroll
        for (int r = 0; r < 4; ++r) {
            const int qp = kg * 4 + r;
            atb[(pcol + qp) * 128 + cb + ct * 16 + l15] = f2bf(acc[r] * invr[r]);
        }
    }
}

// ---------------------------------------------------------------------------
// Output projection: out[o][p] f32 = Wp(hi/lo)[o,:] . attn(bf16)[p,:] + bp[o]
// Wave: 32 rows x 64 cols. Grid (NP/256, 4), 256 threads.
// ---------------------------------------------------------------------------
__global__ __launch_bounds__(256) void gemm_proj(
    const unsigned short* __restrict__ Ahi, const unsigned short* __restrict__ Alo,
    const unsigned short* __restrict__ Bb,
    const float* __restrict__ bias, float* __restrict__ C)
{
    const int lane = threadIdx.x & 63;
    const int wv   = threadIdx.x >> 6;
    const int row0 = blockIdx.y * 32;
    const int colbase = blockIdx.x * 256 + wv * 64;
    const int rlane = lane & 15;
    const int kgrp  = lane >> 4;

    bf16x8 ah0[4], al0[4], ah1[4], al1[4];
    {
        const int ab0 = (row0 + rlane) * 128 + kgrp * 8;
        const int ab1 = (row0 + 16 + rlane) * 128 + kgrp * 8;
        #pragma unroll
        for (int kb = 0; kb < 4; ++kb) {
            ah0[kb] = *(const bf16x8*)(Ahi + ab0 + kb * 32);
            al0[kb] = *(const bf16x8*)(Alo + ab0 + kb * 32);
            ah1[kb] = *(const bf16x8*)(Ahi + ab1 + kb * 32);
            al1[kb] = *(const bf16x8*)(Alo + ab1 + kb * 32);
        }
    }
    float b40[4], b41[4];
    #pragma unroll
    for (int r = 0; r < 4; ++r) {
        b40[r] = bias[row0 + kgrp * 4 + r];
        b41[r] = bias[row0 + 16 + kgrp * 4 + r];
    }

    #pragma unroll
    for (int ct = 0; ct < 4; ++ct) {
        const int p = colbase + ct * 16 + rlane;
        f32x4 acc0 = {0.f, 0.f, 0.f, 0.f};
        f32x4 acc1 = {0.f, 0.f, 0.f, 0.f};
        #pragma unroll
        for (int kb = 0; kb < 4; ++kb) {
            const bf16x8 bh = *(const bf16x8*)(Bb + p * 128 + kb * 32 + kgrp * 8);
            acc0 = __builtin_amdgcn_mfma_f32_16x16x32_bf16(ah0[kb], bh, acc0, 0, 0, 0);
            acc0 = __builtin_amdgcn_mfma_f32_16x16x32_bf16(al0[kb], bh, acc0, 0, 0, 0);
            acc1 = __builtin_amdgcn_mfma_f32_16x16x32_bf16(ah1[kb], bh, acc1, 0, 0, 0);
            acc1 = __builtin_amdgcn_mfma_f32_16x16x32_bf16(al1[kb], bh, acc1, 0, 0, 0);
        }
        #pragma unroll
        for (int r = 0; r < 4; ++r) {
            C[(row0 + kgrp * 4 + r) * NP + p]      = acc0[r] + b40[r];
            C[(row0 + 16 + kgrp * 4 + r) * NP + p] = acc1[r] + b41[r];
        }
    }
}

// ---------------------------------------------------------------------------
extern "C" void kernel_launch(void* const* d_in, const int* in_sizes, int n_in,
                              void* d_out, int out_size, void* d_ws, size_t ws_size,
                              hipStream_t stream)
{
    const float* x    = (const float*)d_in[0];
    const float* Wqkv = (const float*)d_in[1];
    const float* bqkv = (const float*)d_in[2];
    const float* rpb  = (const float*)d_in[3];
    const float* Wp   = (const float*)d_in[4];
    const float* bp   = (const float*)d_in[5];
    float* out = (float*)d_out;

    unsigned short* base = (unsigned short*)d_ws;
    const size_t PL = (size_t)NP * 128;
    unsigned short* xhi = base;
    unsigned short* xlo = base + PL;
    unsigned short* Qb  = base + 2 * PL;
    unsigned short* Kb  = base + 3 * PL;
    unsigned short* VTb = base + 4 * PL;   // [128][NP]
    unsigned short* atb = base + 5 * PL;   // [NP][128]
    unsigned short* wqh = base + 6 * PL;
    unsigned short* wql = wqh + 384 * 128;
    unsigned short* wph = wql + 384 * 128;
    unsigned short* wpl = wph + 128 * 128;

    convert_all<<<dim3(1056), dim3(256), 0, stream>>>(
        x, xhi, xlo, Wqkv, wqh, wql, Wp, wph, wpl);

    qkv_gemm<<<dim3(NP / 256, 12), dim3(256), 0, stream>>>(
        wqh, wql, xhi, xlo, bqkv, Qb, Kb, VTb);

    natten_mfma<<<dim3(4, 32, 4), dim3(512), 0, stream>>>(
        Qb, Kb, VTb, rpb, atb);

    gemm_proj<<<dim3(NP / 256, 4), dim3(256), 0, stream>>>(
        wph, wpl, atb, bp, out);
}

// Round 7
// 47.646 us; speedup vs baseline: 2.2499x; 1.1174x over previous
//
#include <hip/hip_runtime.h>
#include <math.h>

#define NP 16384   // spatial positions = 32*32*16
#define HDIM 32
#define WDIM 32
#define ZDIM 16

typedef short bf16x8 __attribute__((ext_vector_type(8)));
typedef unsigned short u16x8 __attribute__((ext_vector_type(8)));
typedef unsigned short u16x4 __attribute__((ext_vector_type(4)));
typedef float f32x4 __attribute__((ext_vector_type(4)));

__device__ __forceinline__ unsigned short f2bf(float f) {
    unsigned int u = __float_as_uint(f);
    return (unsigned short)((u + 0x7fffu + ((u >> 16) & 1u)) >> 16);
}
__device__ __forceinline__ float bf2f(unsigned short s) {
    return __uint_as_float(((unsigned int)s) << 16);
}

// ---------------------------------------------------------------------------
// Combined conversion kernel.
// Blocks 0..1023: x [128][NP] f32 -> xT bf16 [NP][128] (single plane).
// Blocks 1024..1047: Wqkv hi/lo. 1048..1055: Wp hi/lo.
// ---------------------------------------------------------------------------
__global__ __launch_bounds__(256) void convert_all(
    const float* __restrict__ x, unsigned short* __restrict__ xb,
    const float* __restrict__ Wqkv, unsigned short* __restrict__ wqh,
    unsigned short* __restrict__ wql,
    const float* __restrict__ Wp, unsigned short* __restrict__ wph,
    unsigned short* __restrict__ wpl)
{
    const int b = blockIdx.x;
    if (b < 1024) {
        const int p  = (b >> 4) * 256 + threadIdx.x;
        const int c0 = (b & 15) * 8;
        u16x8 v8;
        #pragma unroll
        for (int j = 0; j < 8; ++j)
            v8[j] = f2bf(x[(c0 + j) * NP + p]);
        *(u16x8*)&xb[p * 128 + c0] = v8;
    } else {
        const float* W; unsigned short *oh, *ol; int e;
        if (b < 1048) {
            W = Wqkv; oh = wqh; ol = wql;
            e = (b - 1024) * 256 + threadIdx.x;
        } else {
            W = Wp; oh = wph; ol = wpl;
            e = (b - 1048) * 256 + threadIdx.x;
        }
        u16x8 vh, vl;
        #pragma unroll
        for (int j = 0; j < 8; ++j) {
            const float v = W[e * 8 + j];
            const unsigned short h = f2bf(v);
            vh[j] = h;
            vl[j] = f2bf(v - bf2f(h));
        }
        *(u16x8*)&oh[e * 8] = vh;
        *(u16x8*)&ol[e * 8] = vl;
    }
}

// ---------------------------------------------------------------------------
// QKV GEMM (hi/lo weights, single-plane bf16 x; bf16 outputs).
// rows 0..127 -> Q[p][ch] (scaled), 128..255 -> K[p][ch], 256..383 -> VT[ch][p].
// Wave computes 32 rows x 64 cols (2 row-groups share B fragments).
// Grid (NP/256, 12), 256 threads.
// ---------------------------------------------------------------------------
__global__ __launch_bounds__(256) void qkv_gemm(
    const unsigned short* __restrict__ Ahi, const unsigned short* __restrict__ Alo,
    const unsigned short* __restrict__ Bb,
    const float* __restrict__ bias,
    unsigned short* __restrict__ Qb, unsigned short* __restrict__ Kb,
    unsigned short* __restrict__ VTb)
{
    const int lane = threadIdx.x & 63;
    const int wv   = threadIdx.x >> 6;
    const int row0 = blockIdx.y * 32;
    const int colbase = blockIdx.x * 256 + wv * 64;
    const int rlane = lane & 15;
    const int kgrp  = lane >> 4;

    bf16x8 ah0[4], al0[4], ah1[4], al1[4];
    {
        const int ab0 = (row0 + rlane) * 128 + kgrp * 8;
        const int ab1 = (row0 + 16 + rlane) * 128 + kgrp * 8;
        #pragma unroll
        for (int kb = 0; kb < 4; ++kb) {
            ah0[kb] = *(const bf16x8*)(Ahi + ab0 + kb * 32);
            al0[kb] = *(const bf16x8*)(Alo + ab0 + kb * 32);
            ah1[kb] = *(const bf16x8*)(Ahi + ab1 + kb * 32);
            al1[kb] = *(const bf16x8*)(Alo + ab1 + kb * 32);
        }
    }
    float b40[4], b41[4];
    #pragma unroll
    for (int r = 0; r < 4; ++r) {
        b40[r] = bias[row0 + kgrp * 4 + r];
        b41[r] = bias[row0 + 16 + kgrp * 4 + r];
    }
    const float rowscale = (row0 < 128) ? 0.17677669529663687f : 1.f;

    #pragma unroll
    for (int ct = 0; ct < 4; ++ct) {
        const int p = colbase + ct * 16 + rlane;
        f32x4 acc0 = {0.f, 0.f, 0.f, 0.f};
        f32x4 acc1 = {0.f, 0.f, 0.f, 0.f};
        #pragma unroll
        for (int kb = 0; kb < 4; ++kb) {
            const bf16x8 bh = *(const bf16x8*)(Bb + p * 128 + kb * 32 + kgrp * 8);
            acc0 = __builtin_amdgcn_mfma_f32_16x16x32_bf16(ah0[kb], bh, acc0, 0, 0, 0);
            acc0 = __builtin_amdgcn_mfma_f32_16x16x32_bf16(al0[kb], bh, acc0, 0, 0, 0);
            acc1 = __builtin_amdgcn_mfma_f32_16x16x32_bf16(ah1[kb], bh, acc1, 0, 0, 0);
            acc1 = __builtin_amdgcn_mfma_f32_16x16x32_bf16(al1[kb], bh, acc1, 0, 0, 0);
        }
        #pragma unroll
        for (int rg = 0; rg < 2; ++rg) {
            const int r0 = row0 + rg * 16;
            unsigned short hh[4];
            #pragma unroll
            for (int r = 0; r < 4; ++r) {
                const float a = rg ? acc1[r] : acc0[r];
                const float bb = rg ? b41[r] : b40[r];
                hh[r] = f2bf((a + bb) * rowscale);
            }
            if (r0 < 128) {
                u16x4 ph = {hh[0], hh[1], hh[2], hh[3]};
                *(u16x4*)&Qb[p * 128 + r0 + kgrp * 4] = ph;
            } else if (r0 < 256) {
                u16x4 ph = {hh[0], hh[1], hh[2], hh[3]};
                *(u16x4*)&Kb[p * 128 + (r0 - 128) + kgrp * 4] = ph;
            } else {
                #pragma unroll
                for (int r = 0; r < 4; ++r)
                    VTb[(r0 - 256 + kgrp * 4 + r) * NP + p] = hh[r];
            }
        }
    }
}

// ---------------------------------------------------------------------------
// MFMA neighborhood attention (single-plane bf16 Q/K/V).
// One wave = one (head, h, w): 16 queries (z) x 144 keys (9 hw-nbrs x 16 z),
// masked to 27 valid per query.  S^T = mfma(K,Q) per key-group (9 MFMA).
// Softmax per q-column (2 shfl_xor).  P bf16 -> per-wave swizzled LDS.
// PV = mfma(P, V^T) (10 MFMA).  Block = 8 waves.  Grid (4, 32, 4).
// ---------------------------------------------------------------------------
#define PROW 320               // 160 keys * 2 B per q-row
#define PWAVE (16 * PROW)      // 5120 B per wave

__global__ __launch_bounds__(512) void natten_mfma(
    const unsigned short* __restrict__ Qb, const unsigned short* __restrict__ Kb,
    const unsigned short* __restrict__ VTb,
    const float* __restrict__ rpb,
    unsigned short* __restrict__ atb)
{
    __shared__ __align__(16) unsigned char Pl[8 * PWAVE];   // 40 KB
    __shared__ float bias_s[128];

    const int tid  = threadIdx.x;
    const int head = blockIdx.z;
    const int h    = blockIdx.y;
    const int wv   = tid >> 6;
    const int w    = blockIdx.x * 8 + wv;
    const int lane = tid & 63;
    const int l15  = lane & 15;
    const int kg   = lane >> 4;

    if (tid < 125) bias_s[tid] = rpb[head * 125 + tid];
    __syncthreads();

    const int hs = min(max(h - 1, 0), HDIM - 3);
    const int ws = min(max(w - 1, 0), WDIM - 3);
    const int rh0 = hs - h + 2, rw0 = ws - w + 2;
    const int pcol = (h * 32 + w) * 16;
    const int cb = head * 32;

    const bf16x8 bq = *(const bf16x8*)&Qb[(pcol + l15) * 128 + cb + kg * 8];

    const int z  = l15;
    const int zs = min(max(z - 1, 0), ZDIM - 3);

    float sv[9][4];
    float m = -1e30f;
    #pragma unroll
    for (int g = 0; g < 9; ++g) {
        const int dh = g / 3, dw = g % 3;
        const int pn = ((hs + dh) * 32 + (ws + dw)) * 16;
        const bf16x8 ak = *(const bf16x8*)&Kb[(pn + l15) * 128 + cb + kg * 8];
        f32x4 st = {0.f, 0.f, 0.f, 0.f};
        st = __builtin_amdgcn_mfma_f32_16x16x32_bf16(ak, bq, st, 0, 0, 0);
        const int bbase = ((rh0 + dh) * 5 + (rw0 + dw)) * 5;
        #pragma unroll
        for (int r = 0; r < 4; ++r) {
            const int zp = kg * 4 + r;            // key z' (D row)
            const int dz = zp - z + 2;
            const bool valid = (zp >= zs) && (zp <= zs + 2);
            const int idx = min(max(dz, 0), 4);
            const float b = valid ? bias_s[bbase + idx] : -1e30f;
            sv[g][r] = st[r] + b;
            m = fmaxf(m, sv[g][r]);
        }
    }
    m = fmaxf(m, __shfl_xor(m, 16, 64));
    m = fmaxf(m, __shfl_xor(m, 32, 64));

    float sum = 0.f;
    #pragma unroll
    for (int g = 0; g < 9; ++g)
        #pragma unroll
        for (int r = 0; r < 4; ++r) {
            sv[g][r] = __expf(sv[g][r] - m);
            sum += sv[g][r];
        }
    sum += __shfl_xor(sum, 16, 64);
    sum += __shfl_xor(sum, 32, 64);
    const float inv = 1.f / sum;

    unsigned char* Pw = &Pl[wv * PWAVE];
    #pragma unroll
    for (int g = 0; g < 9; ++g) {
        u16x4 pk;
        #pragma unroll
        for (int r = 0; r < 4; ++r) pk[r] = f2bf(sv[g][r]);
        const int off = (z * PROW + (16 * g + kg * 4) * 2) ^ ((z & 7) << 4);
        *(u16x4*)(Pw + off) = pk;
    }
    {   // zero-pad keys 144..159
        u16x4 zq = {0, 0, 0, 0};
        const int off = (z * PROW + (144 + kg * 4) * 2) ^ ((z & 7) << 4);
        *(u16x4*)(Pw + off) = zq;
    }

    float invr[4];
    #pragma unroll
    for (int r = 0; r < 4; ++r)
        invr[r] = __shfl(inv, (lane & 48) | (kg * 4 + r), 64);

    #pragma unroll
    for (int ct = 0; ct < 2; ++ct) {
        f32x4 acc = {0.f, 0.f, 0.f, 0.f};
        #pragma unroll
        for (int kb = 0; kb < 5; ++kb) {
            const int off = (z * PROW + (kb * 32 + kg * 8) * 2) ^ ((z & 7) << 4);
            const bf16x8 ap = *(const bf16x8*)(Pw + off);
            const int ga = 2 * kb;
            const int gb = (2 * kb + 1 > 8) ? 8 : 2 * kb + 1;
            const int pna = ((hs + ga / 3) * 32 + (ws + ga % 3)) * 16;
            const int pnbv = ((hs + gb / 3) * 32 + (ws + gb % 3)) * 16;
            const int pn = (kg & 2) ? pnbv : pna;
            const int zoff = (kg & 1) * 8;
            const bf16x8 bv = *(const bf16x8*)&VTb[(cb + ct * 16 + l15) * NP + pn + zoff];
            acc = __builtin_amdgcn_mfma_f32_16x16x32_bf16(ap, bv, acc, 0, 0, 0);
        }
        #pragma unroll
        for (int r = 0; r < 4; ++r) {
            const int qp = kg * 4 + r;
            atb[(pcol + qp) * 128 + cb + ct * 16 + l15] = f2bf(acc[r] * invr[r]);
        }
    }
}

// ---------------------------------------------------------------------------
// Output projection: out[o][p] f32 = Wp(hi/lo)[o,:] . attn(bf16)[p,:] + bp[o]
// Wave: 32 rows x 64 cols. Grid (NP/256, 4), 256 threads.
// ---------------------------------------------------------------------------
__global__ __launch_bounds__(256) void gemm_proj(
    const unsigned short* __restrict__ Ahi, const unsigned short* __restrict__ Alo,
    const unsigned short* __restrict__ Bb,
    const float* __restrict__ bias, float* __restrict__ C)
{
    const int lane = threadIdx.x & 63;
    const int wv   = threadIdx.x >> 6;
    const int row0 = blockIdx.y * 32;
    const int colbase = blockIdx.x * 256 + wv * 64;
    const int rlane = lane & 15;
    const int kgrp  = lane >> 4;

    bf16x8 ah0[4], al0[4], ah1[4], al1[4];
    {
        const int ab0 = (row0 + rlane) * 128 + kgrp * 8;
        const int ab1 = (row0 + 16 + rlane) * 128 + kgrp * 8;
        #pragma unroll
        for (int kb = 0; kb < 4; ++kb) {
            ah0[kb] = *(const bf16x8*)(Ahi + ab0 + kb * 32);
            al0[kb] = *(const bf16x8*)(Alo + ab0 + kb * 32);
            ah1[kb] = *(const bf16x8*)(Ahi + ab1 + kb * 32);
            al1[kb] = *(const bf16x8*)(Alo + ab1 + kb * 32);
        }
    }
    float b40[4], b41[4];
    #pragma unroll
    for (int r = 0; r < 4; ++r) {
        b40[r] = bias[row0 + kgrp * 4 + r];
        b41[r] = bias[row0 + 16 + kgrp * 4 + r];
    }

    #pragma unroll
    for (int ct = 0; ct < 4; ++ct) {
        const int p = colbase + ct * 16 + rlane;
        f32x4 acc0 = {0.f, 0.f, 0.f, 0.f};
        f32x4 acc1 = {0.f, 0.f, 0.f, 0.f};
        #pragma unroll
        for (int kb = 0; kb < 4; ++kb) {
            const bf16x8 bh = *(const bf16x8*)(Bb + p * 128 + kb * 32 + kgrp * 8);
            acc0 = __builtin_amdgcn_mfma_f32_16x16x32_bf16(ah0[kb], bh, acc0, 0, 0, 0);
            acc0 = __builtin_amdgcn_mfma_f32_16x16x32_bf16(al0[kb], bh, acc0, 0, 0, 0);
            acc1 = __builtin_amdgcn_mfma_f32_16x16x32_bf16(ah1[kb], bh, acc1, 0, 0, 0);
            acc1 = __builtin_amdgcn_mfma_f32_16x16x32_bf16(al1[kb], bh, acc1, 0, 0, 0);
        }
        #pragma unroll
        for (int r = 0; r < 4; ++r) {
            C[(row0 + kgrp * 4 + r) * NP + p]      = acc0[r] + b40[r];
            C[(row0 + 16 + kgrp * 4 + r) * NP + p] = acc1[r] + b41[r];
        }
    }
}

// ---------------------------------------------------------------------------
extern "C" void kernel_launch(void* const* d_in, const int* in_sizes, int n_in,
                              void* d_out, int out_size, void* d_ws, size_t ws_size,
                              hipStream_t stream)
{
    const float* x    = (const float*)d_in[0];
    const float* Wqkv = (const float*)d_in[1];
    const float* bqkv = (const float*)d_in[2];
    const float* rpb  = (const float*)d_in[3];
    const float* Wp   = (const float*)d_in[4];
    const float* bp   = (const float*)d_in[5];
    float* out = (float*)d_out;

    unsigned short* base = (unsigned short*)d_ws;
    const size_t PL = (size_t)NP * 128;
    unsigned short* xb  = base;            // [NP][128] bf16
    unsigned short* Qb  = base + 1 * PL;
    unsigned short* Kb  = base + 2 * PL;
    unsigned short* VTb = base + 3 * PL;   // [128][NP]
    unsigned short* atb = base + 4 * PL;   // [NP][128]
    unsigned short* wqh = base + 5 * PL;
    unsigned short* wql = wqh + 384 * 128;
    unsigned short* wph = wql + 384 * 128;
    unsigned short* wpl = wph + 128 * 128;

    convert_all<<<dim3(1056), dim3(256), 0, stream>>>(
        x, xb, Wqkv, wqh, wql, Wp, wph, wpl);

    qkv_gemm<<<dim3(NP / 256, 12), dim3(256), 0, stream>>>(
        wqh, wql, xb, bqkv, Qb, Kb, VTb);

    natten_mfma<<<dim3(4, 32, 4), dim3(512), 0, stream>>>(
        Qb, Kb, VTb, rpb, atb);

    gemm_proj<<<dim3(NP / 256, 4), dim3(256), 0, stream>>>(
        wph, wpl, atb, bp, out);
}

// Round 8
// 46.491 us; speedup vs baseline: 2.3057x; 1.0248x over previous
//
#include <hip/hip_runtime.h>
#include <math.h>

#define NP 16384   // spatial positions = 32*32*16
#define HDIM 32
#define WDIM 32
#define ZDIM 16

typedef short bf16x8 __attribute__((ext_vector_type(8)));
typedef unsigned short u16x8 __attribute__((ext_vector_type(8)));
typedef unsigned short u16x4 __attribute__((ext_vector_type(4)));
typedef float f32x4 __attribute__((ext_vector_type(4)));

__device__ __forceinline__ unsigned short f2bf(float f) {
    unsigned int u = __float_as_uint(f);
    return (unsigned short)((u + 0x7fffu + ((u >> 16) & 1u)) >> 16);
}

// ---------------------------------------------------------------------------
// Combined conversion kernel (all single-plane bf16).
// Blocks 0..1023: x [128][NP] f32 -> xT bf16 [NP][128].
// Blocks 1024..1047: Wqkv. 1048..1055: Wp.
// ---------------------------------------------------------------------------
__global__ __launch_bounds__(256) void convert_all(
    const float* __restrict__ x, unsigned short* __restrict__ xb,
    const float* __restrict__ Wqkv, unsigned short* __restrict__ wqb,
    const float* __restrict__ Wp, unsigned short* __restrict__ wpb)
{
    const int b = blockIdx.x;
    if (b < 1024) {
        const int p  = (b >> 4) * 256 + threadIdx.x;
        const int c0 = (b & 15) * 8;
        u16x8 v8;
        #pragma unroll
        for (int j = 0; j < 8; ++j)
            v8[j] = f2bf(x[(c0 + j) * NP + p]);
        *(u16x8*)&xb[p * 128 + c0] = v8;
    } else {
        const float* W; unsigned short* o; int e;
        if (b < 1048) { W = Wqkv; o = wqb; e = (b - 1024) * 256 + threadIdx.x; }
        else          { W = Wp;   o = wpb; e = (b - 1048) * 256 + threadIdx.x; }
        u16x8 v8;
        #pragma unroll
        for (int j = 0; j < 8; ++j)
            v8[j] = f2bf(W[e * 8 + j]);
        *(u16x8*)&o[e * 8] = v8;
    }
}

// ---------------------------------------------------------------------------
// QKV GEMM (single-plane bf16): rows 0..127 -> Q[p][ch] (scaled),
// 128..255 -> K[p][ch], 256..383 -> VT[ch][p].
// Wave: 32 rows x 64 cols (2 row-groups share B fragments).
// Grid (NP/256, 12), 256 threads.  32 MFMA / wave.
// ---------------------------------------------------------------------------
__global__ __launch_bounds__(256) void qkv_gemm(
    const unsigned short* __restrict__ Ab, const unsigned short* __restrict__ Bb,
    const float* __restrict__ bias,
    unsigned short* __restrict__ Qb, unsigned short* __restrict__ Kb,
    unsigned short* __restrict__ VTb)
{
    const int lane = threadIdx.x & 63;
    const int wv   = threadIdx.x >> 6;
    const int row0 = blockIdx.y * 32;
    const int colbase = blockIdx.x * 256 + wv * 64;
    const int rlane = lane & 15;
    const int kgrp  = lane >> 4;

    bf16x8 a0[4], a1[4];
    {
        const int ab0 = (row0 + rlane) * 128 + kgrp * 8;
        const int ab1 = (row0 + 16 + rlane) * 128 + kgrp * 8;
        #pragma unroll
        for (int kb = 0; kb < 4; ++kb) {
            a0[kb] = *(const bf16x8*)(Ab + ab0 + kb * 32);
            a1[kb] = *(const bf16x8*)(Ab + ab1 + kb * 32);
        }
    }
    float b40[4], b41[4];
    #pragma unroll
    for (int r = 0; r < 4; ++r) {
        b40[r] = bias[row0 + kgrp * 4 + r];
        b41[r] = bias[row0 + 16 + kgrp * 4 + r];
    }
    const float rowscale = (row0 < 128) ? 0.17677669529663687f : 1.f;

    #pragma unroll
    for (int ct = 0; ct < 4; ++ct) {
        const int p = colbase + ct * 16 + rlane;
        f32x4 acc0 = {0.f, 0.f, 0.f, 0.f};
        f32x4 acc1 = {0.f, 0.f, 0.f, 0.f};
        #pragma unroll
        for (int kb = 0; kb < 4; ++kb) {
            const bf16x8 bh = *(const bf16x8*)(Bb + p * 128 + kb * 32 + kgrp * 8);
            acc0 = __builtin_amdgcn_mfma_f32_16x16x32_bf16(a0[kb], bh, acc0, 0, 0, 0);
            acc1 = __builtin_amdgcn_mfma_f32_16x16x32_bf16(a1[kb], bh, acc1, 0, 0, 0);
        }
        #pragma unroll
        for (int rg = 0; rg < 2; ++rg) {
            const int r0 = row0 + rg * 16;
            unsigned short hh[4];
            #pragma unroll
            for (int r = 0; r < 4; ++r) {
                const float a = rg ? acc1[r] : acc0[r];
                const float bb = rg ? b41[r] : b40[r];
                hh[r] = f2bf((a + bb) * rowscale);
            }
            if (r0 < 128) {
                u16x4 ph = {hh[0], hh[1], hh[2], hh[3]};
                *(u16x4*)&Qb[p * 128 + r0 + kgrp * 4] = ph;
            } else if (r0 < 256) {
                u16x4 ph = {hh[0], hh[1], hh[2], hh[3]};
                *(u16x4*)&Kb[p * 128 + (r0 - 128) + kgrp * 4] = ph;
            } else {
                #pragma unroll
                for (int r = 0; r < 4; ++r)
                    VTb[(r0 - 256 + kgrp * 4 + r) * NP + p] = hh[r];
            }
        }
    }
}

// ---------------------------------------------------------------------------
// MFMA neighborhood attention (single-plane bf16 Q/K/V).
// One wave = one (head, h, w): 16 queries (z) x 144 keys (9 hw-nbrs x 16 z).
// Per-lane z-mask/bias-index hoisted out of the QK loop; all 36 bias values
// preloaded into registers before the K-load chain; invalid keys masked by
// multiplying P with 0 after exp (softmax-invariant under max shift).
// Block = 8 waves.  Grid (4, 32, 4).
// ---------------------------------------------------------------------------
#define PROW 320               // 160 keys * 2 B per q-row
#define PWAVE (16 * PROW)      // 5120 B per wave

__global__ __launch_bounds__(512) void natten_mfma(
    const unsigned short* __restrict__ Qb, const unsigned short* __restrict__ Kb,
    const unsigned short* __restrict__ VTb,
    const float* __restrict__ rpb,
    unsigned short* __restrict__ atb)
{
    __shared__ __align__(16) unsigned char Pl[8 * PWAVE];   // 40 KB
    __shared__ float bias_s[128];

    const int tid  = threadIdx.x;
    const int head = blockIdx.z;
    const int h    = blockIdx.y;
    const int wv   = tid >> 6;
    const int w    = blockIdx.x * 8 + wv;
    const int lane = tid & 63;
    const int l15  = lane & 15;
    const int kg   = lane >> 4;

    if (tid < 125) bias_s[tid] = rpb[head * 125 + tid];
    __syncthreads();

    const int hs = min(max(h - 1, 0), HDIM - 3);
    const int ws = min(max(w - 1, 0), WDIM - 3);
    const int rh0 = hs - h + 2, rw0 = ws - w + 2;
    const int pcol = (h * 32 + w) * 16;
    const int cb = head * 32;

    const bf16x8 bq = *(const bf16x8*)&Qb[(pcol + l15) * 128 + cb + kg * 8];

    const int z  = l15;
    const int zs = min(max(z - 1, 0), ZDIM - 3);

    // per-lane z-window mask + clamped bias index (loop-invariant over g)
    int   idxc[4];
    float vmask[4];
    #pragma unroll
    for (int r = 0; r < 4; ++r) {
        const int zp = kg * 4 + r;
        const int dz = zp - z + 2;
        idxc[r]  = min(max(dz, 0), 4);
        vmask[r] = (zp >= zs && zp <= zs + 2) ? 1.f : 0.f;
    }
    // preload all 36 bias values (independent LDS reads, off the QK chain)
    float biasv[9][4];
    #pragma unroll
    for (int g = 0; g < 9; ++g) {
        const int bbase = ((rh0 + g / 3) * 5 + (rw0 + g % 3)) * 5;
        #pragma unroll
        for (int r = 0; r < 4; ++r)
            biasv[g][r] = bias_s[bbase + idxc[r]];
    }

    float sv[9][4];
    float m = -1e30f;
    #pragma unroll
    for (int g = 0; g < 9; ++g) {
        const int dh = g / 3, dw = g % 3;
        const int pn = ((hs + dh) * 32 + (ws + dw)) * 16;
        const bf16x8 ak = *(const bf16x8*)&Kb[(pn + l15) * 128 + cb + kg * 8];
        f32x4 st = {0.f, 0.f, 0.f, 0.f};
        st = __builtin_amdgcn_mfma_f32_16x16x32_bf16(ak, bq, st, 0, 0, 0);
        #pragma unroll
        for (int r = 0; r < 4; ++r) {
            sv[g][r] = st[r] + biasv[g][r];
            m = fmaxf(m, sv[g][r]);
        }
    }
    m = fmaxf(m, __shfl_xor(m, 16, 64));
    m = fmaxf(m, __shfl_xor(m, 32, 64));

    float sum = 0.f;
    #pragma unroll
    for (int g = 0; g < 9; ++g)
        #pragma unroll
        for (int r = 0; r < 4; ++r) {
            sv[g][r] = __expf(sv[g][r] - m) * vmask[r];
            sum += sv[g][r];
        }
    sum += __shfl_xor(sum, 16, 64);
    sum += __shfl_xor(sum, 32, 64);
    const float inv = 1.f / sum;

    unsigned char* Pw = &Pl[wv * PWAVE];
    #pragma unroll
    for (int g = 0; g < 9; ++g) {
        u16x4 pk;
        #pragma unroll
        for (int r = 0; r < 4; ++r) pk[r] = f2bf(sv[g][r]);
        const int off = (z * PROW + (16 * g + kg * 4) * 2) ^ ((z & 7) << 4);
        *(u16x4*)(Pw + off) = pk;
    }
    {   // zero-pad keys 144..159
        u16x4 zq = {0, 0, 0, 0};
        const int off = (z * PROW + (144 + kg * 4) * 2) ^ ((z & 7) << 4);
        *(u16x4*)(Pw + off) = zq;
    }

    float invr[4];
    #pragma unroll
    for (int r = 0; r < 4; ++r)
        invr[r] = __shfl(inv, (lane & 48) | (kg * 4 + r), 64);

    #pragma unroll
    for (int ct = 0; ct < 2; ++ct) {
        f32x4 acc = {0.f, 0.f, 0.f, 0.f};
        #pragma unroll
        for (int kb = 0; kb < 5; ++kb) {
            const int off = (z * PROW + (kb * 32 + kg * 8) * 2) ^ ((z & 7) << 4);
            const bf16x8 ap = *(const bf16x8*)(Pw + off);
            const int ga = 2 * kb;
            const int gb = (2 * kb + 1 > 8) ? 8 : 2 * kb + 1;
            const int pna = ((hs + ga / 3) * 32 + (ws + ga % 3)) * 16;
            const int pnbv = ((hs + gb / 3) * 32 + (ws + gb % 3)) * 16;
            const int pn = (kg & 2) ? pnbv : pna;
            const int zoff = (kg & 1) * 8;
            const bf16x8 bv = *(const bf16x8*)&VTb[(cb + ct * 16 + l15) * NP + pn + zoff];
            acc = __builtin_amdgcn_mfma_f32_16x16x32_bf16(ap, bv, acc, 0, 0, 0);
        }
        #pragma unroll
        for (int r = 0; r < 4; ++r) {
            const int qp = kg * 4 + r;
            atb[(pcol + qp) * 128 + cb + ct * 16 + l15] = f2bf(acc[r] * invr[r]);
        }
    }
}

// ---------------------------------------------------------------------------
// Output projection: out[o][p] f32 = Wp(bf16)[o,:] . attn(bf16)[p,:] + bp[o]
// Wave: 16 rows x 64 cols. Grid (NP/256, 8), 256 threads.  16 MFMA / wave.
// ---------------------------------------------------------------------------
__global__ __launch_bounds__(256) void gemm_proj(
    const unsigned short* __restrict__ Ab, const unsigned short* __restrict__ Bb,
    const float* __restrict__ bias, float* __restrict__ C)
{
    const int lane = threadIdx.x & 63;
    const int wv   = threadIdx.x >> 6;
    const int row0 = blockIdx.y * 16;
    const int colbase = blockIdx.x * 256 + wv * 64;
    const int rlane = lane & 15;
    const int kgrp  = lane >> 4;

    bf16x8 a[4];
    {
        const int ab = (row0 + rlane) * 128 + kgrp * 8;
        #pragma unroll
        for (int kb = 0; kb < 4; ++kb)
            a[kb] = *(const bf16x8*)(Ab + ab + kb * 32);
    }
    float b4[4];
    #pragma unroll
    for (int r = 0; r < 4; ++r) b4[r] = bias[row0 + kgrp * 4 + r];

    #pragma unroll
    for (int ct = 0; ct < 4; ++ct) {
        const int p = colbase + ct * 16 + rlane;
        f32x4 acc = {0.f, 0.f, 0.f, 0.f};
        #pragma unroll
        for (int kb = 0; kb < 4; ++kb) {
            const bf16x8 bh = *(const bf16x8*)(Bb + p * 128 + kb * 32 + kgrp * 8);
            acc = __builtin_amdgcn_mfma_f32_16x16x32_bf16(a[kb], bh, acc, 0, 0, 0);
        }
        #pragma unroll
        for (int r = 0; r < 4; ++r)
            C[(row0 + kgrp * 4 + r) * NP + p] = acc[r] + b4[r];
    }
}

// ---------------------------------------------------------------------------
extern "C" void kernel_launch(void* const* d_in, const int* in_sizes, int n_in,
                              void* d_out, int out_size, void* d_ws, size_t ws_size,
                              hipStream_t stream)
{
    const float* x    = (const float*)d_in[0];
    const float* Wqkv = (const float*)d_in[1];
    const float* bqkv = (const float*)d_in[2];
    const float* rpb  = (const float*)d_in[3];
    const float* Wp   = (const float*)d_in[4];
    const float* bp   = (const float*)d_in[5];
    float* out = (float*)d_out;

    unsigned short* base = (unsigned short*)d_ws;
    const size_t PL = (size_t)NP * 128;
    unsigned short* xb  = base;            // [NP][128] bf16
    unsigned short* Qb  = base + 1 * PL;
    unsigned short* Kb  = base + 2 * PL;
    unsigned short* VTb = base + 3 * PL;   // [128][NP]
    unsigned short* atb = base + 4 * PL;   // [NP][128]
    unsigned short* wqb = base + 5 * PL;
    unsigned short* wpb = wqb + 384 * 128;

    convert_all<<<dim3(1056), dim3(256), 0, stream>>>(
        x, xb, Wqkv, wqb, Wp, wpb);

    qkv_gemm<<<dim3(NP / 256, 12), dim3(256), 0, stream>>>(
        wqb, xb, bqkv, Qb, Kb, VTb);

    natten_mfma<<<dim3(4, 32, 4), dim3(512), 0, stream>>>(
        Qb, Kb, VTb, rpb, atb);

    gemm_proj<<<dim3(NP / 256, 8), dim3(256), 0, stream>>>(
        wpb, atb, bp, out);
}

// Round 9
// 43.398 us; speedup vs baseline: 2.4701x; 1.0713x over previous
//
#include <hip/hip_runtime.h>
#include <math.h>

#define NP 16384   // spatial positions = 32*32*16
#define HDIM 32
#define WDIM 32
#define ZDIM 16

typedef short bf16x8 __attribute__((ext_vector_type(8)));
typedef unsigned short u16x8 __attribute__((ext_vector_type(8)));
typedef unsigned short u16x4 __attribute__((ext_vector_type(4)));
typedef float f32x4 __attribute__((ext_vector_type(4)));

__device__ __forceinline__ unsigned short f2bf(float f) {
    unsigned int u = __float_as_uint(f);
    return (unsigned short)((u + 0x7fffu + ((u >> 16) & 1u)) >> 16);
}

// ---------------------------------------------------------------------------
// Combined conversion kernel (all single-plane bf16).
// Blocks 0..1023: x [128][NP] f32 -> xT bf16 [NP][128].
// Blocks 1024..1047: Wqkv. 1048..1055: Wp.
// ---------------------------------------------------------------------------
__global__ __launch_bounds__(256) void convert_all(
    const float* __restrict__ x, unsigned short* __restrict__ xb,
    const float* __restrict__ Wqkv, unsigned short* __restrict__ wqb,
    const float* __restrict__ Wp, unsigned short* __restrict__ wpb)
{
    const int b = blockIdx.x;
    if (b < 1024) {
        const int p  = (b >> 4) * 256 + threadIdx.x;
        const int c0 = (b & 15) * 8;
        u16x8 v8;
        #pragma unroll
        for (int j = 0; j < 8; ++j)
            v8[j] = f2bf(x[(c0 + j) * NP + p]);
        *(u16x8*)&xb[p * 128 + c0] = v8;
    } else {
        const float* W; unsigned short* o; int e;
        if (b < 1048) { W = Wqkv; o = wqb; e = (b - 1024) * 256 + threadIdx.x; }
        else          { W = Wp;   o = wpb; e = (b - 1048) * 256 + threadIdx.x; }
        u16x8 v8;
        #pragma unroll
        for (int j = 0; j < 8; ++j)
            v8[j] = f2bf(W[e * 8 + j]);
        *(u16x8*)&o[e * 8] = v8;
    }
}

// ---------------------------------------------------------------------------
// QKV GEMM (single-plane bf16): rows 0..127 -> Q[p][ch] (scaled),
// 128..255 -> K[p][ch], 256..383 -> VT[ch][p].
// Wave: 32 rows x 64 cols (2 row-groups share B fragments).
// Grid (NP/256, 12), 256 threads.  32 MFMA / wave.
// ---------------------------------------------------------------------------
__global__ __launch_bounds__(256) void qkv_gemm(
    const unsigned short* __restrict__ Ab, const unsigned short* __restrict__ Bb,
    const float* __restrict__ bias,
    unsigned short* __restrict__ Qb, unsigned short* __restrict__ Kb,
    unsigned short* __restrict__ VTb)
{
    const int lane = threadIdx.x & 63;
    const int wv   = threadIdx.x >> 6;
    const int row0 = blockIdx.y * 32;
    const int colbase = blockIdx.x * 256 + wv * 64;
    const int rlane = lane & 15;
    const int kgrp  = lane >> 4;

    bf16x8 a0[4], a1[4];
    {
        const int ab0 = (row0 + rlane) * 128 + kgrp * 8;
        const int ab1 = (row0 + 16 + rlane) * 128 + kgrp * 8;
        #pragma unroll
        for (int kb = 0; kb < 4; ++kb) {
            a0[kb] = *(const bf16x8*)(Ab + ab0 + kb * 32);
            a1[kb] = *(const bf16x8*)(Ab + ab1 + kb * 32);
        }
    }
    float b40[4], b41[4];
    #pragma unroll
    for (int r = 0; r < 4; ++r) {
        b40[r] = bias[row0 + kgrp * 4 + r];
        b41[r] = bias[row0 + 16 + kgrp * 4 + r];
    }
    const float rowscale = (row0 < 128) ? 0.17677669529663687f : 1.f;

    #pragma unroll
    for (int ct = 0; ct < 4; ++ct) {
        const int p = colbase + ct * 16 + rlane;
        f32x4 acc0 = {0.f, 0.f, 0.f, 0.f};
        f32x4 acc1 = {0.f, 0.f, 0.f, 0.f};
        #pragma unroll
        for (int kb = 0; kb < 4; ++kb) {
            const bf16x8 bh = *(const bf16x8*)(Bb + p * 128 + kb * 32 + kgrp * 8);
            acc0 = __builtin_amdgcn_mfma_f32_16x16x32_bf16(a0[kb], bh, acc0, 0, 0, 0);
            acc1 = __builtin_amdgcn_mfma_f32_16x16x32_bf16(a1[kb], bh, acc1, 0, 0, 0);
        }
        #pragma unroll
        for (int rg = 0; rg < 2; ++rg) {
            const int r0 = row0 + rg * 16;
            unsigned short hh[4];
            #pragma unroll
            for (int r = 0; r < 4; ++r) {
                const float a = rg ? acc1[r] : acc0[r];
                const float bb = rg ? b41[r] : b40[r];
                hh[r] = f2bf((a + bb) * rowscale);
            }
            if (r0 < 128) {
                u16x4 ph = {hh[0], hh[1], hh[2], hh[3]};
                *(u16x4*)&Qb[p * 128 + r0 + kgrp * 4] = ph;
            } else if (r0 < 256) {
                u16x4 ph = {hh[0], hh[1], hh[2], hh[3]};
                *(u16x4*)&Kb[p * 128 + (r0 - 128) + kgrp * 4] = ph;
            } else {
                #pragma unroll
                for (int r = 0; r < 4; ++r)
                    VTb[(r0 - 256 + kgrp * 4 + r) * NP + p] = hh[r];
            }
        }
    }
}

// ---------------------------------------------------------------------------
// Fused MFMA neighborhood attention + output projection.
// Block = 8 waves (512 thr): wave wv -> (head = wv>>1, wcol = wv&1),
// covering all 4 heads of 32 consecutive positions (2 w-columns x 16 z).
// Phase 1 (per wave, as before): 16 queries x 144 keys, S^T = mfma(K,Q),
// softmax (2 shfl_xor), P -> per-wave swizzled LDS, PV = mfma(P, V^T).
// Attention output (bf16) -> swizzled LDS tile As[32 pos][128 ch].
// Phase 2: out[o][p] = Wp[o,:] . As[p,:] + bp[o]; wave computes 16 rows x
// 32 cols (8 MFMA), direct f32 stores.  Grid (16, 32).
// ---------------------------------------------------------------------------
#define PROW 320               // 160 keys * 2 B per q-row
#define PWAVE (16 * PROW)      // 5120 B per wave

__global__ __launch_bounds__(512) void natten_proj(
    const unsigned short* __restrict__ Qb, const unsigned short* __restrict__ Kb,
    const unsigned short* __restrict__ VTb,
    const float* __restrict__ rpb,
    const unsigned short* __restrict__ Wpb, const float* __restrict__ bp,
    float* __restrict__ out)
{
    __shared__ __align__(16) unsigned char Pl[8 * PWAVE];   // 40 KB
    __shared__ __align__(16) unsigned char As[32 * 256];    //  8 KB attn tile
    __shared__ float bias_s[500];                           //  2 KB (4 heads)

    const int tid  = threadIdx.x;
    const int h    = blockIdx.y;
    const int wv   = tid >> 6;
    const int head = wv >> 1;
    const int wcol = wv & 1;
    const int w    = blockIdx.x * 2 + wcol;
    const int lane = tid & 63;
    const int l15  = lane & 15;
    const int kg   = lane >> 4;

    if (tid < 500) bias_s[tid] = rpb[tid];
    __syncthreads();

    const int hs = min(max(h - 1, 0), HDIM - 3);
    const int ws = min(max(w - 1, 0), WDIM - 3);
    const int rh0 = hs - h + 2, rw0 = ws - w + 2;
    const int pcolw = (h * 32 + w) * 16;      // this wave's 16 positions
    const int cb = head * 32;

    const bf16x8 bq = *(const bf16x8*)&Qb[(pcolw + l15) * 128 + cb + kg * 8];

    const int z  = l15;
    const int zs = min(max(z - 1, 0), ZDIM - 3);

    // per-lane z-window mask + clamped bias index (loop-invariant over g)
    int   idxc[4];
    float vmask[4];
    #pragma unroll
    for (int r = 0; r < 4; ++r) {
        const int zp = kg * 4 + r;
        const int dz = zp - z + 2;
        idxc[r]  = min(max(dz, 0), 4);
        vmask[r] = (zp >= zs && zp <= zs + 2) ? 1.f : 0.f;
    }
    float biasv[9][4];
    #pragma unroll
    for (int g = 0; g < 9; ++g) {
        const int bbase = head * 125 + ((rh0 + g / 3) * 5 + (rw0 + g % 3)) * 5;
        #pragma unroll
        for (int r = 0; r < 4; ++r)
            biasv[g][r] = bias_s[bbase + idxc[r]];
    }

    float sv[9][4];
    float m = -1e30f;
    #pragma unroll
    for (int g = 0; g < 9; ++g) {
        const int dh = g / 3, dw = g % 3;
        const int pn = ((hs + dh) * 32 + (ws + dw)) * 16;
        const bf16x8 ak = *(const bf16x8*)&Kb[(pn + l15) * 128 + cb + kg * 8];
        f32x4 st = {0.f, 0.f, 0.f, 0.f};
        st = __builtin_amdgcn_mfma_f32_16x16x32_bf16(ak, bq, st, 0, 0, 0);
        #pragma unroll
        for (int r = 0; r < 4; ++r) {
            sv[g][r] = st[r] + biasv[g][r];
            m = fmaxf(m, sv[g][r]);
        }
    }
    m = fmaxf(m, __shfl_xor(m, 16, 64));
    m = fmaxf(m, __shfl_xor(m, 32, 64));

    float sum = 0.f;
    #pragma unroll
    for (int g = 0; g < 9; ++g)
        #pragma unroll
        for (int r = 0; r < 4; ++r) {
            sv[g][r] = __expf(sv[g][r] - m) * vmask[r];
            sum += sv[g][r];
        }
    sum += __shfl_xor(sum, 16, 64);
    sum += __shfl_xor(sum, 32, 64);
    const float inv = 1.f / sum;

    unsigned char* Pw = &Pl[wv * PWAVE];
    #pragma unroll
    for (int g = 0; g < 9; ++g) {
        u16x4 pk;
        #pragma unroll
        for (int r = 0; r < 4; ++r) pk[r] = f2bf(sv[g][r]);
        const int off = (z * PROW + (16 * g + kg * 4) * 2) ^ ((z & 7) << 4);
        *(u16x4*)(Pw + off) = pk;
    }
    {   // zero-pad keys 144..159
        u16x4 zq = {0, 0, 0, 0};
        const int off = (z * PROW + (144 + kg * 4) * 2) ^ ((z & 7) << 4);
        *(u16x4*)(Pw + off) = zq;
    }

    float invr[4];
    #pragma unroll
    for (int r = 0; r < 4; ++r)
        invr[r] = __shfl(inv, (lane & 48) | (kg * 4 + r), 64);

    // PV -> attention output into swizzled LDS tile As
    #pragma unroll
    for (int ct = 0; ct < 2; ++ct) {
        f32x4 acc = {0.f, 0.f, 0.f, 0.f};
        #pragma unroll
        for (int kb = 0; kb < 5; ++kb) {
            const int off = (z * PROW + (kb * 32 + kg * 8) * 2) ^ ((z & 7) << 4);
            const bf16x8 ap = *(const bf16x8*)(Pw + off);
            const int ga = 2 * kb;
            const int gb = (2 * kb + 1 > 8) ? 8 : 2 * kb + 1;
            const int pna = ((hs + ga / 3) * 32 + (ws + ga % 3)) * 16;
            const int pnbv = ((hs + gb / 3) * 32 + (ws + gb % 3)) * 16;
            const int pn = (kg & 2) ? pnbv : pna;
            const int zoff = (kg & 1) * 8;
            const bf16x8 bv = *(const bf16x8*)&VTb[(cb + ct * 16 + l15) * NP + pn + zoff];
            acc = __builtin_amdgcn_mfma_f32_16x16x32_bf16(ap, bv, acc, 0, 0, 0);
        }
        #pragma unroll
        for (int r = 0; r < 4; ++r) {
            const int pl = wcol * 16 + kg * 4 + r;         // local position 0..31
            const int ch = cb + ct * 16 + l15;             // channel 0..127
            const int byte = pl * 256 + ((ch * 2) ^ ((pl & 7) << 4));
            *(unsigned short*)(As + byte) = f2bf(acc[r] * invr[r]);
        }
    }

    __syncthreads();

    // ---- Phase 2: projection.  Wave wv computes out rows wv*16..+15 for the
    // block's 32 positions.  A = Wp rows (bf16), B = As (swizzled LDS).
    const int row0 = wv * 16;
    bf16x8 a[4];
    {
        const int ab = (row0 + l15) * 128 + kg * 8;
        #pragma unroll
        for (int kb = 0; kb < 4; ++kb)
            a[kb] = *(const bf16x8*)(Wpb + ab + kb * 32);
    }
    float b4[4];
    #pragma unroll
    for (int r = 0; r < 4; ++r) b4[r] = bp[row0 + kg * 4 + r];

    const int pcol0 = (h * 32 + blockIdx.x * 2) * 16;      // block's first position

    #pragma unroll
    for (int ct = 0; ct < 2; ++ct) {
        const int pl = ct * 16 + l15;
        f32x4 acc = {0.f, 0.f, 0.f, 0.f};
        #pragma unroll
        for (int kb = 0; kb < 4; ++kb) {
            const int byte = pl * 256 + ((kb * 64 + kg * 16) ^ ((pl & 7) << 4));
            const bf16x8 bh = *(const bf16x8*)(As + byte);
            acc = __builtin_amdgcn_mfma_f32_16x16x32_bf16(a[kb], bh, acc, 0, 0, 0);
        }
        #pragma unroll
        for (int r = 0; r < 4; ++r)
            out[(row0 + kg * 4 + r) * NP + pcol0 + ct * 16 + l15] = acc[r] + b4[r];
    }
}

// ---------------------------------------------------------------------------
extern "C" void kernel_launch(void* const* d_in, const int* in_sizes, int n_in,
                              void* d_out, int out_size, void* d_ws, size_t ws_size,
                              hipStream_t stream)
{
    const float* x    = (const float*)d_in[0];
    const float* Wqkv = (const float*)d_in[1];
    const float* bqkv = (const float*)d_in[2];
    const float* rpb  = (const float*)d_in[3];
    const float* Wp   = (const float*)d_in[4];
    const float* bp   = (const float*)d_in[5];
    float* out = (float*)d_out;

    unsigned short* base = (unsigned short*)d_ws;
    const size_t PL = (size_t)NP * 128;
    unsigned short* xb  = base;            // [NP][128] bf16
    unsigned short* Qb  = base + 1 * PL;
    unsigned short* Kb  = base + 2 * PL;
    unsigned short* VTb = base + 3 * PL;   // [128][NP]
    unsigned short* wqb = base + 4 * PL;
    unsigned short* wpb = wqb + 384 * 128;

    convert_all<<<dim3(1056), dim3(256), 0, stream>>>(
        x, xb, Wqkv, wqb, Wp, wpb);

    qkv_gemm<<<dim3(NP / 256, 12), dim3(256), 0, stream>>>(
        wqb, xb, bqkv, Qb, Kb, VTb);

    natten_proj<<<dim3(16, 32), dim3(512), 0, stream>>>(
        Qb, Kb, VTb, rpb, wpb, bp, out);
}

// Round 10
// 40.546 us; speedup vs baseline: 2.6438x; 1.0703x over previous
//
#include <hip/hip_runtime.h>
#include <math.h>

#define NP 16384   // spatial positions = 32*32*16
#define HDIM 32
#define WDIM 32
#define ZDIM 16

typedef short bf16x8 __attribute__((ext_vector_type(8)));
typedef unsigned short u16x8 __attribute__((ext_vector_type(8)));
typedef unsigned short u16x4 __attribute__((ext_vector_type(4)));
typedef float f32x4 __attribute__((ext_vector_type(4)));

__device__ __forceinline__ unsigned short f2bf(float f) {
    unsigned int u = __float_as_uint(f);
    return (unsigned short)((u + 0x7fffu + ((u >> 16) & 1u)) >> 16);
}

// pack 8 consecutive f32 -> bf16x8 (two float4 loads)
__device__ __forceinline__ bf16x8 cvt8(const float* __restrict__ p) {
    const float4 w0 = *(const float4*)p;
    const float4 w1 = *(const float4*)(p + 4);
    bf16x8 v;
    v[0] = (short)f2bf(w0.x); v[1] = (short)f2bf(w0.y);
    v[2] = (short)f2bf(w0.z); v[3] = (short)f2bf(w0.w);
    v[4] = (short)f2bf(w1.x); v[5] = (short)f2bf(w1.y);
    v[6] = (short)f2bf(w1.z); v[7] = (short)f2bf(w1.w);
    return v;
}

// ---------------------------------------------------------------------------
// Fused convert + QKV GEMM.
// Block (512 thr, 8 waves) covers 128 positions.  Stage x f32 [128ch][128p]
// -> swizzled LDS bf16 [p][ch] (32 KB), convert Wqkv A-fragments f32->bf16
// in-register.  Wave wv computes rows wv*48..+47 (3 tiles of 16) x 128 cols.
// Outputs: rows 0..127 -> Q[p][ch] (scaled), 128..255 -> K[p][ch],
// 256..383 -> VT[ch][p].  Grid (NP/128) = 128 blocks.
// ---------------------------------------------------------------------------
__global__ __launch_bounds__(512) void qkv_fused(
    const float* __restrict__ x, const float* __restrict__ Wqkv,
    const float* __restrict__ bias,
    unsigned short* __restrict__ Qb, unsigned short* __restrict__ Kb,
    unsigned short* __restrict__ VTb)
{
    __shared__ __align__(16) unsigned char Xs[128 * 256];   // 32 KB

    const int tid = threadIdx.x;
    const int p0  = blockIdx.x * 128;

    // stage + convert x: 128 pos x 16 ch-groups = 2048 items, 4 per thread
    #pragma unroll
    for (int it = 0; it < 4; ++it) {
        const int item = tid + it * 512;
        const int pl   = item & 127;
        const int c0   = (item >> 7) * 8;
        u16x8 v8;
        #pragma unroll
        for (int j = 0; j < 8; ++j)
            v8[j] = f2bf(x[(c0 + j) * NP + p0 + pl]);
        const int byte = pl * 256 + ((c0 * 2) ^ ((pl & 7) << 4));
        *(u16x8*)(Xs + byte) = v8;
    }

    const int lane = tid & 63;
    const int wv   = tid >> 6;
    const int l15  = lane & 15;
    const int kg   = lane >> 4;
    const int wrow = wv * 48;          // this wave's first output row

    // A fragments (3 row-tiles x 4 k-blocks), converted from f32 in-register
    bf16x8 a[3][4];
    float  b4[3][4];
    #pragma unroll
    for (int t = 0; t < 3; ++t) {
        const int row = wrow + t * 16 + l15;
        #pragma unroll
        for (int kb = 0; kb < 4; ++kb)
            a[t][kb] = cvt8(&Wqkv[row * 128 + kb * 32 + kg * 8]);
        #pragma unroll
        for (int r = 0; r < 4; ++r)
            b4[t][r] = bias[wrow + t * 16 + kg * 4 + r];
    }
    __syncthreads();

    #pragma unroll
    for (int ct = 0; ct < 8; ++ct) {
        const int pl = ct * 16 + l15;
        bf16x8 bfr[4];
        #pragma unroll
        for (int kb = 0; kb < 4; ++kb) {
            const int byte = pl * 256 + ((kb * 64 + kg * 16) ^ ((pl & 7) << 4));
            bfr[kb] = *(const bf16x8*)(Xs + byte);
        }
        const int p = p0 + pl;
        #pragma unroll
        for (int t = 0; t < 3; ++t) {
            f32x4 acc = {0.f, 0.f, 0.f, 0.f};
            #pragma unroll
            for (int kb = 0; kb < 4; ++kb)
                acc = __builtin_amdgcn_mfma_f32_16x16x32_bf16(a[t][kb], bfr[kb], acc, 0, 0, 0);
            const int r0 = wrow + t * 16;
            const float rowscale = (r0 < 128) ? 0.17677669529663687f : 1.f;
            unsigned short hh[4];
            #pragma unroll
            for (int r = 0; r < 4; ++r)
                hh[r] = f2bf((acc[r] + b4[t][r]) * rowscale);
            if (r0 < 128) {
                u16x4 ph = {hh[0], hh[1], hh[2], hh[3]};
                *(u16x4*)&Qb[p * 128 + r0 + kg * 4] = ph;
            } else if (r0 < 256) {
                u16x4 ph = {hh[0], hh[1], hh[2], hh[3]};
                *(u16x4*)&Kb[p * 128 + (r0 - 128) + kg * 4] = ph;
            } else {
                #pragma unroll
                for (int r = 0; r < 4; ++r)
                    VTb[(r0 - 256 + kg * 4 + r) * NP + p] = hh[r];
            }
        }
    }
}

// ---------------------------------------------------------------------------
// Fused MFMA neighborhood attention + output projection.
// Block = 8 waves (512 thr): wave wv -> (head = wv>>1, wcol = wv&1),
// covering all 4 heads of 32 consecutive positions (2 w-columns x 16 z).
// Phase 1: 16 queries x 144 keys, S^T = mfma(K,Q), softmax (2 shfl_xor),
// P -> per-wave swizzled LDS, PV = mfma(P, V^T); attn out (bf16) ->
// swizzled LDS tile As[32 pos][128 ch].
// Phase 2: out[o][p] = Wp[o,:] . As[p,:] + bp[o]; Wp read f32, packed to
// bf16 in-register BEFORE phase 1 (latency hidden under QK^T).
// Grid (16, 32), 512 threads.
// ---------------------------------------------------------------------------
#define PROW 320               // 160 keys * 2 B per q-row
#define PWAVE (16 * PROW)      // 5120 B per wave

__global__ __launch_bounds__(512) void natten_proj(
    const unsigned short* __restrict__ Qb, const unsigned short* __restrict__ Kb,
    const unsigned short* __restrict__ VTb,
    const float* __restrict__ rpb,
    const float* __restrict__ Wp, const float* __restrict__ bp,
    float* __restrict__ out)
{
    __shared__ __align__(16) unsigned char Pl[8 * PWAVE];   // 40 KB
    __shared__ __align__(16) unsigned char As[32 * 256];    //  8 KB attn tile
    __shared__ float bias_s[500];                           //  2 KB (4 heads)

    const int tid  = threadIdx.x;
    const int h    = blockIdx.y;
    const int wv   = tid >> 6;
    const int head = wv >> 1;
    const int wcol = wv & 1;
    const int w    = blockIdx.x * 2 + wcol;
    const int lane = tid & 63;
    const int l15  = lane & 15;
    const int kg   = lane >> 4;

    if (tid < 500) bias_s[tid] = rpb[tid];
    __syncthreads();

    const int hs = min(max(h - 1, 0), HDIM - 3);
    const int ws = min(max(w - 1, 0), WDIM - 3);
    const int rh0 = hs - h + 2, rw0 = ws - w + 2;
    const int pcolw = (h * 32 + w) * 16;      // this wave's 16 positions
    const int cb = head * 32;

    // --- phase-2 operands loaded early (independent; hides under phase 1)
    const int prow0 = wv * 16;                // projection output rows
    bf16x8 aw[4];
    {
        const int ab = (prow0 + l15) * 128 + kg * 8;
        #pragma unroll
        for (int kb = 0; kb < 4; ++kb)
            aw[kb] = cvt8(&Wp[ab + kb * 32]);
    }
    float bpr[4];
    #pragma unroll
    for (int r = 0; r < 4; ++r) bpr[r] = bp[prow0 + kg * 4 + r];

    const bf16x8 bq = *(const bf16x8*)&Qb[(pcolw + l15) * 128 + cb + kg * 8];

    const int z  = l15;
    const int zs = min(max(z - 1, 0), ZDIM - 3);

    // per-lane z-window mask + clamped bias index (loop-invariant over g)
    int   idxc[4];
    float vmask[4];
    #pragma unroll
    for (int r = 0; r < 4; ++r) {
        const int zp = kg * 4 + r;
        const int dz = zp - z + 2;
        idxc[r]  = min(max(dz, 0), 4);
        vmask[r] = (zp >= zs && zp <= zs + 2) ? 1.f : 0.f;
    }
    float biasv[9][4];
    #pragma unroll
    for (int g = 0; g < 9; ++g) {
        const int bbase = head * 125 + ((rh0 + g / 3) * 5 + (rw0 + g % 3)) * 5;
        #pragma unroll
        for (int r = 0; r < 4; ++r)
            biasv[g][r] = bias_s[bbase + idxc[r]];
    }

    float sv[9][4];
    float m = -1e30f;
    #pragma unroll
    for (int g = 0; g < 9; ++g) {
        const int dh = g / 3, dw = g % 3;
        const int pn = ((hs + dh) * 32 + (ws + dw)) * 16;
        const bf16x8 ak = *(const bf16x8*)&Kb[(pn + l15) * 128 + cb + kg * 8];
        f32x4 st = {0.f, 0.f, 0.f, 0.f};
        st = __builtin_amdgcn_mfma_f32_16x16x32_bf16(ak, bq, st, 0, 0, 0);
        #pragma unroll
        for (int r = 0; r < 4; ++r) {
            sv[g][r] = st[r] + biasv[g][r];
            m = fmaxf(m, sv[g][r]);
        }
    }
    m = fmaxf(m, __shfl_xor(m, 16, 64));
    m = fmaxf(m, __shfl_xor(m, 32, 64));

    float sum = 0.f;
    #pragma unroll
    for (int g = 0; g < 9; ++g)
        #pragma unroll
        for (int r = 0; r < 4; ++r) {
            sv[g][r] = __expf(sv[g][r] - m) * vmask[r];
            sum += sv[g][r];
        }
    sum += __shfl_xor(sum, 16, 64);
    sum += __shfl_xor(sum, 32, 64);
    const float inv = 1.f / sum;

    unsigned char* Pw = &Pl[wv * PWAVE];
    #pragma unroll
    for (int g = 0; g < 9; ++g) {
        u16x4 pk;
        #pragma unroll
        for (int r = 0; r < 4; ++r) pk[r] = f2bf(sv[g][r]);
        const int off = (z * PROW + (16 * g + kg * 4) * 2) ^ ((z & 7) << 4);
        *(u16x4*)(Pw + off) = pk;
    }
    {   // zero-pad keys 144..159
        u16x4 zq = {0, 0, 0, 0};
        const int off = (z * PROW + (144 + kg * 4) * 2) ^ ((z & 7) << 4);
        *(u16x4*)(Pw + off) = zq;
    }

    float invr[4];
    #pragma unroll
    for (int r = 0; r < 4; ++r)
        invr[r] = __shfl(inv, (lane & 48) | (kg * 4 + r), 64);

    // PV -> attention output into swizzled LDS tile As
    #pragma unroll
    for (int ct = 0; ct < 2; ++ct) {
        f32x4 acc = {0.f, 0.f, 0.f, 0.f};
        #pragma unroll
        for (int kb = 0; kb < 5; ++kb) {
            const int off = (z * PROW + (kb * 32 + kg * 8) * 2) ^ ((z & 7) << 4);
            const bf16x8 ap = *(const bf16x8*)(Pw + off);
            const int ga = 2 * kb;
            const int gb = (2 * kb + 1 > 8) ? 8 : 2 * kb + 1;
            const int pna = ((hs + ga / 3) * 32 + (ws + ga % 3)) * 16;
            const int pnbv = ((hs + gb / 3) * 32 + (ws + gb % 3)) * 16;
            const int pn = (kg & 2) ? pnbv : pna;
            const int zoff = (kg & 1) * 8;
            const bf16x8 bv = *(const bf16x8*)&VTb[(cb + ct * 16 + l15) * NP + pn + zoff];
            acc = __builtin_amdgcn_mfma_f32_16x16x32_bf16(ap, bv, acc, 0, 0, 0);
        }
        #pragma unroll
        for (int r = 0; r < 4; ++r) {
            const int pl = wcol * 16 + kg * 4 + r;         // local position 0..31
            const int ch = cb + ct * 16 + l15;             // channel 0..127
            const int byte = pl * 256 + ((ch * 2) ^ ((pl & 7) << 4));
            *(unsigned short*)(As + byte) = f2bf(acc[r] * invr[r]);
        }
    }

    __syncthreads();

    // ---- Phase 2: projection.  Wave wv computes out rows prow0..+15 for the
    // block's 32 positions.
    const int pcol0 = (h * 32 + blockIdx.x * 2) * 16;      // block's first position

    #pragma unroll
    for (int ct = 0; ct < 2; ++ct) {
        const int pl = ct * 16 + l15;
        f32x4 acc = {0.f, 0.f, 0.f, 0.f};
        #pragma unroll
        for (int kb = 0; kb < 4; ++kb) {
            const int byte = pl * 256 + ((kb * 64 + kg * 16) ^ ((pl & 7) << 4));
            const bf16x8 bh = *(const bf16x8*)(As + byte);
            acc = __builtin_amdgcn_mfma_f32_16x16x32_bf16(aw[kb], bh, acc, 0, 0, 0);
        }
        #pragma unroll
        for (int r = 0; r < 4; ++r)
            out[(prow0 + kg * 4 + r) * NP + pcol0 + ct * 16 + l15] = acc[r] + bpr[r];
    }
}

// ---------------------------------------------------------------------------
extern "C" void kernel_launch(void* const* d_in, const int* in_sizes, int n_in,
                              void* d_out, int out_size, void* d_ws, size_t ws_size,
                              hipStream_t stream)
{
    const float* x    = (const float*)d_in[0];
    const float* Wqkv = (const float*)d_in[1];
    const float* bqkv = (const float*)d_in[2];
    const float* rpb  = (const float*)d_in[3];
    const float* Wp   = (const float*)d_in[4];
    const float* bp   = (const float*)d_in[5];
    float* out = (float*)d_out;

    unsigned short* base = (unsigned short*)d_ws;
    const size_t PL = (size_t)NP * 128;
    unsigned short* Qb  = base;            // [NP][128] bf16
    unsigned short* Kb  = base + 1 * PL;
    unsigned short* VTb = base + 2 * PL;   // [128][NP]

    qkv_fused<<<dim3(NP / 128), dim3(512), 0, stream>>>(
        x, Wqkv, bqkv, Qb, Kb, VTb);

    natten_proj<<<dim3(16, 32), dim3(512), 0, stream>>>(
        Qb, Kb, VTb, rpb, Wp, bp, out);
}

// Round 11
// 37.944 us; speedup vs baseline: 2.8251x; 1.0686x over previous
//
#include <hip/hip_runtime.h>
#include <math.h>

#define NP 16384   // spatial positions = 32*32*16
#define HDIM 32
#define WDIM 32
#define ZDIM 16

typedef short bf16x8 __attribute__((ext_vector_type(8)));
typedef unsigned short u16x8 __attribute__((ext_vector_type(8)));
typedef unsigned short u16x4 __attribute__((ext_vector_type(4)));
typedef float f32x4 __attribute__((ext_vector_type(4)));

__device__ __forceinline__ unsigned short f2bf(float f) {
    unsigned int u = __float_as_uint(f);
    return (unsigned short)((u + 0x7fffu + ((u >> 16) & 1u)) >> 16);
}

// pack 8 consecutive f32 -> bf16x8 (two float4 loads)
__device__ __forceinline__ bf16x8 cvt8(const float* __restrict__ p) {
    const float4 w0 = *(const float4*)p;
    const float4 w1 = *(const float4*)(p + 4);
    bf16x8 v;
    v[0] = (short)f2bf(w0.x); v[1] = (short)f2bf(w0.y);
    v[2] = (short)f2bf(w0.z); v[3] = (short)f2bf(w0.w);
    v[4] = (short)f2bf(w1.x); v[5] = (short)f2bf(w1.y);
    v[6] = (short)f2bf(w1.z); v[7] = (short)f2bf(w1.w);
    return v;
}

// ---------------------------------------------------------------------------
// Fused convert + QKV GEMM.
// Block (512 thr, 8 waves) covers 64 positions.  Stage x f32 -> swizzled LDS
// bf16 [p][ch] (16 KB), convert Wqkv A-fragments f32->bf16 in-register.
// Wave wv computes rows wv*48..+47 (3 tiles of 16) x 64 cols (4 col-tiles).
// Outputs: rows 0..127 -> Q[p][ch] (scaled), 128..255 -> K[p][ch],
// 256..383 -> VT[ch][p].  Grid (NP/64) = 256 blocks -> all CUs active.
// ---------------------------------------------------------------------------
__global__ __launch_bounds__(512) void qkv_fused(
    const float* __restrict__ x, const float* __restrict__ Wqkv,
    const float* __restrict__ bias,
    unsigned short* __restrict__ Qb, unsigned short* __restrict__ Kb,
    unsigned short* __restrict__ VTb)
{
    __shared__ __align__(16) unsigned char Xs[64 * 256];   // 16 KB

    const int tid = threadIdx.x;
    const int p0  = blockIdx.x * 64;

    // stage + convert x: 64 pos x 16 ch-groups = 1024 items, 2 per thread
    #pragma unroll
    for (int it = 0; it < 2; ++it) {
        const int item = tid + it * 512;
        const int pl   = item & 63;
        const int c0   = (item >> 6) * 8;
        u16x8 v8;
        #pragma unroll
        for (int j = 0; j < 8; ++j)
            v8[j] = f2bf(x[(c0 + j) * NP + p0 + pl]);
        const int byte = pl * 256 + ((c0 * 2) ^ ((pl & 7) << 4));
        *(u16x8*)(Xs + byte) = v8;
    }

    const int lane = tid & 63;
    const int wv   = tid >> 6;
    const int l15  = lane & 15;
    const int kg   = lane >> 4;
    const int wrow = wv * 48;          // this wave's first output row

    // A fragments (3 row-tiles x 4 k-blocks), converted from f32 in-register
    bf16x8 a[3][4];
    float  b4[3][4];
    #pragma unroll
    for (int t = 0; t < 3; ++t) {
        const int row = wrow + t * 16 + l15;
        #pragma unroll
        for (int kb = 0; kb < 4; ++kb)
            a[t][kb] = cvt8(&Wqkv[row * 128 + kb * 32 + kg * 8]);
        #pragma unroll
        for (int r = 0; r < 4; ++r)
            b4[t][r] = bias[wrow + t * 16 + kg * 4 + r];
    }
    __syncthreads();

    #pragma unroll
    for (int ct = 0; ct < 4; ++ct) {
        const int pl = ct * 16 + l15;
        bf16x8 bfr[4];
        #pragma unroll
        for (int kb = 0; kb < 4; ++kb) {
            const int byte = pl * 256 + ((kb * 64 + kg * 16) ^ ((pl & 7) << 4));
            bfr[kb] = *(const bf16x8*)(Xs + byte);
        }
        const int p = p0 + pl;
        #pragma unroll
        for (int t = 0; t < 3; ++t) {
            f32x4 acc = {0.f, 0.f, 0.f, 0.f};
            __builtin_amdgcn_s_setprio(1);
            #pragma unroll
            for (int kb = 0; kb < 4; ++kb)
                acc = __builtin_amdgcn_mfma_f32_16x16x32_bf16(a[t][kb], bfr[kb], acc, 0, 0, 0);
            __builtin_amdgcn_s_setprio(0);
            const int r0 = wrow + t * 16;
            const float rowscale = (r0 < 128) ? 0.17677669529663687f : 1.f;
            unsigned short hh[4];
            #pragma unroll
            for (int r = 0; r < 4; ++r)
                hh[r] = f2bf((acc[r] + b4[t][r]) * rowscale);
            if (r0 < 128) {
                u16x4 ph = {hh[0], hh[1], hh[2], hh[3]};
                *(u16x4*)&Qb[p * 128 + r0 + kg * 4] = ph;
            } else if (r0 < 256) {
                u16x4 ph = {hh[0], hh[1], hh[2], hh[3]};
                *(u16x4*)&Kb[p * 128 + (r0 - 128) + kg * 4] = ph;
            } else {
                #pragma unroll
                for (int r = 0; r < 4; ++r)
                    VTb[(r0 - 256 + kg * 4 + r) * NP + p] = hh[r];
            }
        }
    }
}

// ---------------------------------------------------------------------------
// Fused MFMA neighborhood attention + output projection.
// Block = 8 waves (512 thr): wave wv -> (head = wv>>1, wcol = wv&1),
// covering all 4 heads of 32 consecutive positions (2 w-columns x 16 z).
// Phase 1: 16 queries x 144 keys, S^T = mfma(K,Q), softmax (2 shfl_xor),
// P -> per-wave swizzled LDS, PV = mfma(P, V^T); attn out (bf16) ->
// swizzled LDS tile As[32 pos][128 ch].
// Phase 2: out[o][p] = Wp[o,:] . As[p,:] + bp[o]; Wp read f32, packed to
// bf16 in-register BEFORE phase 1 (latency hidden under QK^T).
// Grid (16, 32), 512 threads.  s_setprio(1) wraps MFMA clusters (T5).
// ---------------------------------------------------------------------------
#define PROW 320               // 160 keys * 2 B per q-row
#define PWAVE (16 * PROW)      // 5120 B per wave

__global__ __launch_bounds__(512) void natten_proj(
    const unsigned short* __restrict__ Qb, const unsigned short* __restrict__ Kb,
    const unsigned short* __restrict__ VTb,
    const float* __restrict__ rpb,
    const float* __restrict__ Wp, const float* __restrict__ bp,
    float* __restrict__ out)
{
    __shared__ __align__(16) unsigned char Pl[8 * PWAVE];   // 40 KB
    __shared__ __align__(16) unsigned char As[32 * 256];    //  8 KB attn tile
    __shared__ float bias_s[500];                           //  2 KB (4 heads)

    const int tid  = threadIdx.x;
    const int h    = blockIdx.y;
    const int wv   = tid >> 6;
    const int head = wv >> 1;
    const int wcol = wv & 1;
    const int w    = blockIdx.x * 2 + wcol;
    const int lane = tid & 63;
    const int l15  = lane & 15;
    const int kg   = lane >> 4;

    if (tid < 500) bias_s[tid] = rpb[tid];
    __syncthreads();

    const int hs = min(max(h - 1, 0), HDIM - 3);
    const int ws = min(max(w - 1, 0), WDIM - 3);
    const int rh0 = hs - h + 2, rw0 = ws - w + 2;
    const int pcolw = (h * 32 + w) * 16;      // this wave's 16 positions
    const int cb = head * 32;

    // --- phase-2 operands loaded early (independent; hides under phase 1)
    const int prow0 = wv * 16;                // projection output rows
    bf16x8 aw[4];
    {
        const int ab = (prow0 + l15) * 128 + kg * 8;
        #pragma unroll
        for (int kb = 0; kb < 4; ++kb)
            aw[kb] = cvt8(&Wp[ab + kb * 32]);
    }
    float bpr[4];
    #pragma unroll
    for (int r = 0; r < 4; ++r) bpr[r] = bp[prow0 + kg * 4 + r];

    const bf16x8 bq = *(const bf16x8*)&Qb[(pcolw + l15) * 128 + cb + kg * 8];

    const int z  = l15;
    const int zs = min(max(z - 1, 0), ZDIM - 3);

    // per-lane z-window mask + clamped bias index (loop-invariant over g)
    int   idxc[4];
    float vmask[4];
    #pragma unroll
    for (int r = 0; r < 4; ++r) {
        const int zp = kg * 4 + r;
        const int dz = zp - z + 2;
        idxc[r]  = min(max(dz, 0), 4);
        vmask[r] = (zp >= zs && zp <= zs + 2) ? 1.f : 0.f;
    }
    float biasv[9][4];
    #pragma unroll
    for (int g = 0; g < 9; ++g) {
        const int bbase = head * 125 + ((rh0 + g / 3) * 5 + (rw0 + g % 3)) * 5;
        #pragma unroll
        for (int r = 0; r < 4; ++r)
            biasv[g][r] = bias_s[bbase + idxc[r]];
    }

    float sv[9][4];
    float m = -1e30f;
    __builtin_amdgcn_s_setprio(1);
    #pragma unroll
    for (int g = 0; g < 9; ++g) {
        const int dh = g / 3, dw = g % 3;
        const int pn = ((hs + dh) * 32 + (ws + dw)) * 16;
        const bf16x8 ak = *(const bf16x8*)&Kb[(pn + l15) * 128 + cb + kg * 8];
        f32x4 st = {0.f, 0.f, 0.f, 0.f};
        st = __builtin_amdgcn_mfma_f32_16x16x32_bf16(ak, bq, st, 0, 0, 0);
        #pragma unroll
        for (int r = 0; r < 4; ++r) {
            sv[g][r] = st[r] + biasv[g][r];
            m = fmaxf(m, sv[g][r]);
        }
    }
    __builtin_amdgcn_s_setprio(0);
    m = fmaxf(m, __shfl_xor(m, 16, 64));
    m = fmaxf(m, __shfl_xor(m, 32, 64));

    float sum = 0.f;
    #pragma unroll
    for (int g = 0; g < 9; ++g)
        #pragma unroll
        for (int r = 0; r < 4; ++r) {
            sv[g][r] = __expf(sv[g][r] - m) * vmask[r];
            sum += sv[g][r];
        }
    sum += __shfl_xor(sum, 16, 64);
    sum += __shfl_xor(sum, 32, 64);
    const float inv = 1.f / sum;

    unsigned char* Pw = &Pl[wv * PWAVE];
    #pragma unroll
    for (int g = 0; g < 9; ++g) {
        u16x4 pk;
        #pragma unroll
        for (int r = 0; r < 4; ++r) pk[r] = f2bf(sv[g][r]);
        const int off = (z * PROW + (16 * g + kg * 4) * 2) ^ ((z & 7) << 4);
        *(u16x4*)(Pw + off) = pk;
    }
    {   // zero-pad keys 144..159
        u16x4 zq = {0, 0, 0, 0};
        const int off = (z * PROW + (144 + kg * 4) * 2) ^ ((z & 7) << 4);
        *(u16x4*)(Pw + off) = zq;
    }

    float invr[4];
    #pragma unroll
    for (int r = 0; r < 4; ++r)
        invr[r] = __shfl(inv, (lane & 48) | (kg * 4 + r), 64);

    // PV -> attention output into swizzled LDS tile As
    #pragma unroll
    for (int ct = 0; ct < 2; ++ct) {
        f32x4 acc = {0.f, 0.f, 0.f, 0.f};
        __builtin_amdgcn_s_setprio(1);
        #pragma unroll
        for (int kb = 0; kb < 5; ++kb) {
            const int off = (z * PROW + (kb * 32 + kg * 8) * 2) ^ ((z & 7) << 4);
            const bf16x8 ap = *(const bf16x8*)(Pw + off);
            const int ga = 2 * kb;
            const int gb = (2 * kb + 1 > 8) ? 8 : 2 * kb + 1;
            const int pna = ((hs + ga / 3) * 32 + (ws + ga % 3)) * 16;
            const int pnbv = ((hs + gb / 3) * 32 + (ws + gb % 3)) * 16;
            const int pn = (kg & 2) ? pnbv : pna;
            const int zoff = (kg & 1) * 8;
            const bf16x8 bv = *(const bf16x8*)&VTb[(cb + ct * 16 + l15) * NP + pn + zoff];
            acc = __builtin_amdgcn_mfma_f32_16x16x32_bf16(ap, bv, acc, 0, 0, 0);
        }
        __builtin_amdgcn_s_setprio(0);
        #pragma unroll
        for (int r = 0; r < 4; ++r) {
            const int pl = wcol * 16 + kg * 4 + r;         // local position 0..31
            const int ch = cb + ct * 16 + l15;             // channel 0..127
            const int byte = pl * 256 + ((ch * 2) ^ ((pl & 7) << 4));
            *(unsigned short*)(As + byte) = f2bf(acc[r] * invr[r]);
        }
    }

    __syncthreads();

    // ---- Phase 2: projection.  Wave wv computes out rows prow0..+15 for the
    // block's 32 positions.
    const int pcol0 = (h * 32 + blockIdx.x * 2) * 16;      // block's first position

    #pragma unroll
    for (int ct = 0; ct < 2; ++ct) {
        const int pl = ct * 16 + l15;
        f32x4 acc = {0.f, 0.f, 0.f, 0.f};
        #pragma unroll
        for (int kb = 0; kb < 4; ++kb) {
            const int byte = pl * 256 + ((kb * 64 + kg * 16) ^ ((pl & 7) << 4));
            const bf16x8 bh = *(const bf16x8*)(As + byte);
            acc = __builtin_amdgcn_mfma_f32_16x16x32_bf16(aw[kb], bh, acc, 0, 0, 0);
        }
        #pragma unroll
        for (int r = 0; r < 4; ++r)
            out[(prow0 + kg * 4 + r) * NP + pcol0 + ct * 16 + l15] = acc[r] + bpr[r];
    }
}

// ---------------------------------------------------------------------------
extern "C" void kernel_launch(void* const* d_in, const int* in_sizes, int n_in,
                              void* d_out, int out_size, void* d_ws, size_t ws_size,
                              hipStream_t stream)
{
    const float* x    = (const float*)d_in[0];
    const float* Wqkv = (const float*)d_in[1];
    const float* bqkv = (const float*)d_in[2];
    const float* rpb  = (const float*)d_in[3];
    const float* Wp   = (const float*)d_in[4];
    const float* bp   = (const float*)d_in[5];
    float* out = (float*)d_out;

    unsigned short* base = (unsigned short*)d_ws;
    const size_t PL = (size_t)NP * 128;
    unsigned short* Qb  = base;            // [NP][128] bf16
    unsigned short* Kb  = base + 1 * PL;
    unsigned short* VTb = base + 2 * PL;   // [128][NP]

    qkv_fused<<<dim3(NP / 64), dim3(512), 0, stream>>>(
        x, Wqkv, bqkv, Qb, Kb, VTb);

    natten_proj<<<dim3(16, 32), dim3(512), 0, stream>>>(
        Qb, Kb, VTb, rpb, Wp, bp, out);
}